// Round 1
// baseline (862.999 us; speedup 1.0000x reference)
//
#include <hip/hip_runtime.h>
#include <math.h>

#define HOP   240
#define T_IN  72000
#define NB    4
#define NF    300
#define NCB   8
#define CBS   1024
#define CBD   64

// Output layout (flat float32):
// a_tokens (4,8,300)        @ 0       .. 9600
// b_logits (4,4,300,64)     @ 9600    .. 316800
// s1       (4,1,6)          @ 316800  .. 316824
// s2       (4,64,4)         @ 316824  .. 317848
// s3       (4,128,4)        @ 317848  .. 319896
// s4       (4,256,2)        @ 319896  .. 321944
#define OFF_LOG 9600
#define OFF_S1  316800
#define OFF_S2  316824
#define OFF_S3  317848
#define OFF_S4  319896

__device__ __forceinline__ float elu1(float x) {
    return x > 0.f ? x : expm1f(x);
}

__global__ __launch_bounds__(256)
void enc_fused_kernel(const float* __restrict__ audio,
                      const float* __restrict__ w1, const float* __restrict__ b1,
                      const float* __restrict__ w2, const float* __restrict__ b2,
                      const float* __restrict__ w3, const float* __restrict__ b3,
                      const float* __restrict__ w4, const float* __restrict__ b4,
                      const float* __restrict__ cbs,
                      const float* __restrict__ hw, const float* __restrict__ hb,
                      float* __restrict__ out)
{
    const int tid = threadIdx.x;
    const int bf  = blockIdx.x;          // 0..1199
    const int b   = bf / NF;
    const int f   = bf - b * NF;
    const int t   = f * HOP + (HOP - 1); // kept sample index, 239..71999

    __shared__ float ash[17];        // audio[t-16 .. t]
    __shared__ float y1s[11 * 64];   // conv1+elu at positions t-10..t, [pos][ch]
    __shared__ float y2s[7 * 128];   // conv2+elu at t-6..t
    __shared__ float y3s[3 * 256];   // conv3+elu at t-2..t
    __shared__ float zs[512];        // conv4+elu at t (the frame vector z)
    __shared__ float zqs[512];       // quantized z (concat of chosen codes)
    __shared__ float rs[64];         // RVQ residual
    __shared__ float red_d[256];
    __shared__ int   red_i[256];

    // ---- stage audio window ----
    if (tid < 17) ash[tid] = audio[b * T_IN + (t - 16) + tid];
    __syncthreads();

    // ---- conv1 (1->64, k=7) + elu at 11 positions ----
    for (int j = tid; j < 11 * 64; j += 256) {
        const int p = j >> 6;   // position offset 0..10  (abs pos t-10+p)
        const int o = j & 63;
        float acc = b1[o];
        #pragma unroll
        for (int k = 0; k < 7; ++k)
            acc += w1[o * 7 + k] * ash[p + k];   // audio[(t-10+p)-6+k] = ash[p+k]
        y1s[p * 64 + o] = elu1(acc);
    }
    __syncthreads();

    // ---- conv2 (64->128, k=5) + elu at 7 positions ----
    // 256 threads = 128 channels x 2 input-channel halves; partial sums via LDS
    {
        const int c    = tid & 127;
        const int half = tid >> 7;
        float acc[7];
        #pragma unroll
        for (int p = 0; p < 7; ++p) acc[p] = 0.f;
        const float* wrow = w2 + c * (64 * 5) + half * (32 * 5);
        for (int i = 0; i < 32; ++i) {
            const int ii = half * 32 + i;
            #pragma unroll
            for (int k = 0; k < 5; ++k) {
                const float w = wrow[i * 5 + k];
                #pragma unroll
                for (int p = 0; p < 7; ++p)
                    acc[p] += w * y1s[(p + k) * 64 + ii];  // y1 at (t-6+p)-4+k -> idx p+k
            }
        }
        if (half == 1) {
            #pragma unroll
            for (int p = 0; p < 7; ++p) y2s[p * 128 + c] = acc[p];
        }
        __syncthreads();
        if (half == 0) {
            #pragma unroll
            for (int p = 0; p < 7; ++p) {
                const float v = acc[p] + y2s[p * 128 + c] + b2[c];
                y2s[p * 128 + c] = elu1(v);
            }
        }
        __syncthreads();
    }

    // ---- conv3 (128->256, k=5) + elu at 3 positions ----
    {
        const int c = tid;
        float a0 = b3[c], a1 = b3[c], a2 = b3[c];
        const float* wrow = w3 + c * (128 * 5);
        for (int i = 0; i < 128; ++i) {
            #pragma unroll
            for (int k = 0; k < 5; ++k) {
                const float w = wrow[i * 5 + k];
                a0 += w * y2s[(0 + k) * 128 + i];   // y2 at (t-2+p)-4+k -> idx p+k
                a1 += w * y2s[(1 + k) * 128 + i];
                a2 += w * y2s[(2 + k) * 128 + i];
            }
        }
        y3s[0 * 256 + c] = elu1(a0);
        y3s[1 * 256 + c] = elu1(a1);
        y3s[2 * 256 + c] = elu1(a2);
    }
    __syncthreads();

    // ---- conv4 (256->512, k=3) + elu at position t ----
    #pragma unroll
    for (int cc = 0; cc < 2; ++cc) {
        const int c = tid + cc * 256;
        float acc = b4[c];
        const float* wrow = w4 + c * (256 * 3);
        for (int i = 0; i < 256; ++i) {
            #pragma unroll
            for (int k = 0; k < 3; ++k)
                acc += wrow[i * 3 + k] * y3s[k * 256 + i];
        }
        zs[c] = elu1(acc);
    }
    __syncthreads();

    // ---- RVQ: 8 sequential codebook stages ----
    if (tid < 64) rs[tid] = zs[tid];
    __syncthreads();

    for (int s = 0; s < NCB; ++s) {
        // ||r||^2 (redundant per thread; LDS broadcast, cheap)
        float rn = 0.f;
        #pragma unroll
        for (int j = 0; j < 64; ++j) { const float rj = rs[j]; rn += rj * rj; }

        const float* cb = cbs + s * (CBS * CBD);
        float bestd = 3.402823466e38f;
        int   besti = 0x7fffffff;
        #pragma unroll
        for (int q = 0; q < 4; ++q) {
            const int c = tid + q * 256;
            const float* cv = cb + c * CBD;
            float dot = 0.f, nn = 0.f;
            #pragma unroll 8
            for (int j = 0; j < CBD; ++j) {
                const float w = cv[j];
                dot += w * rs[j];
                nn  += w * w;
            }
            const float d = rn + nn - 2.f * dot;
            if (d < bestd || (d == bestd && c < besti)) { bestd = d; besti = c; }
        }
        red_d[tid] = bestd; red_i[tid] = besti;
        __syncthreads();
        for (int st = 128; st > 0; st >>= 1) {
            if (tid < st) {
                const float d2 = red_d[tid + st]; const int i2 = red_i[tid + st];
                if (d2 < red_d[tid] || (d2 == red_d[tid] && i2 < red_i[tid])) {
                    red_d[tid] = d2; red_i[tid] = i2;
                }
            }
            __syncthreads();
        }
        const int idx = red_i[0];
        if (tid == 0) out[b * (NCB * NF) + s * NF + f] = (float)idx;
        if (tid < 64) {
            const float qv = cb[idx * CBD + tid];
            zqs[s * 64 + tid] = qv;
            if (s < NCB - 1) rs[tid] = zs[(s + 1) * 64 + tid] + (rs[tid] - qv);
        }
        __syncthreads();
    }

    // ---- head: logits[b,h,f,o] = sum_d zq[d]*hw[h,o,d] + hb[h,o] ----
    {
        const int h = tid >> 6, o = tid & 63;
        float acc = hb[h * 64 + o];
        const float* wrow = hw + (h * 64 + o) * 512;
        #pragma unroll 8
        for (int d = 0; d < 512; ++d) acc += wrow[d] * zqs[d];
        out[OFF_LOG + ((b * 4 + h) * NF + f) * 64 + o] = acc;
    }

    // ---- streaming tails (only last frame per batch) ----
    if (f == NF - 1) {
        if (tid < 6) out[OFF_S1 + b * 6 + tid] = audio[b * T_IN + (T_IN - 6) + tid];
        // s2: elu(conv1) at 71996..71999 -> p = 7+j
        out[OFF_S2 + b * 256 + tid] = y1s[(7 + (tid & 3)) * 64 + (tid >> 2)];
        // s3: elu(conv2) at 71996..71999 -> p2 = 3+j
        for (int j = tid; j < 512; j += 256)
            out[OFF_S3 + b * 512 + j] = y2s[(3 + (j & 3)) * 128 + (j >> 2)];
        // s4: elu(conv3) at 71998..71999 -> p3 = 1+j
        for (int j = tid; j < 512; j += 256)
            out[OFF_S4 + b * 512 + j] = y3s[(1 + (j & 1)) * 256 + (j >> 1)];
    }
}

extern "C" void kernel_launch(void* const* d_in, const int* in_sizes, int n_in,
                              void* d_out, int out_size, void* d_ws, size_t ws_size,
                              hipStream_t stream) {
    const float* audio = (const float*)d_in[0];
    const float* w1 = (const float*)d_in[1];
    const float* b1 = (const float*)d_in[2];
    const float* w2 = (const float*)d_in[3];
    const float* b2 = (const float*)d_in[4];
    const float* w3 = (const float*)d_in[5];
    const float* b3 = (const float*)d_in[6];
    const float* w4 = (const float*)d_in[7];
    const float* b4 = (const float*)d_in[8];
    const float* cbs = (const float*)d_in[9];
    const float* hw = (const float*)d_in[10];
    const float* hb = (const float*)d_in[11];
    float* out = (float*)d_out;

    dim3 grid(NB * NF);   // 1200 blocks: one per (batch, kept frame)
    dim3 block(256);
    enc_fused_kernel<<<grid, block, 0, stream>>>(audio, w1, b1, w2, b2, w3, b3,
                                                 w4, b4, cbs, hw, hb, out);
}

// Round 2
// 665.360 us; speedup vs baseline: 1.2970x; 1.2970x over previous
//
#include <hip/hip_runtime.h>
#include <math.h>

#define HOP   240
#define T_IN  72000
#define NB    4
#define NF    300
#define NCB   8
#define CBS   1024
#define CBD   64

// Output layout (flat float32):
// a_tokens (4,8,300)        @ 0
// b_logits (4,4,300,64)     @ 9600
// s1 (4,1,6) @316800  s2 (4,64,4) @316824  s3 (4,128,4) @317848  s4 (4,256,2) @319896
#define OFF_LOG 9600
#define OFF_S1  316800
#define OFF_S2  316824
#define OFF_S3  317848
#define OFF_S4  319896

__device__ __forceinline__ float elu1(float x) { return x > 0.f ? x : expm1f(x); }

// sum across a 16-lane group (lanes 16g..16g+15 of a wave); result in all 16 lanes
__device__ __forceinline__ float red16(float v) {
    v += __shfl_xor(v, 1);
    v += __shfl_xor(v, 2);
    v += __shfl_xor(v, 4);
    v += __shfl_xor(v, 8);
    return v;
}

__device__ __forceinline__ float dot4(float4 a, float4 b) {
    return a.x * b.x + a.y * b.y + a.z * b.z + a.w * b.w;
}

// ---- tiny pre-kernel: codebook norms (cb**2).sum(-1) into ws ----
__global__ __launch_bounds__(256)
void cb_norms_kernel(const float* __restrict__ cbs, float* __restrict__ nrm) {
    const int g = threadIdx.x >> 4, sub = threadIdx.x & 15;
    const int code = blockIdx.x * 16 + g;           // 0..8191
    const float4 v = *reinterpret_cast<const float4*>(cbs + code * CBD + (sub << 2));
    float s = red16(v.x * v.x + v.y * v.y + v.z * v.z + v.w * v.w);
    if (sub == 0) nrm[code] = s;
}

__global__ __launch_bounds__(256)
void enc_fused_kernel(const float* __restrict__ audio,
                      const float* __restrict__ w1, const float* __restrict__ b1,
                      const float* __restrict__ w2, const float* __restrict__ b2,
                      const float* __restrict__ w3, const float* __restrict__ b3,
                      const float* __restrict__ w4, const float* __restrict__ b4,
                      const float* __restrict__ cbs,
                      const float* __restrict__ hw, const float* __restrict__ hb,
                      const float* __restrict__ nrm,   // 8192 norms or nullptr
                      float* __restrict__ out)
{
    const int tid = threadIdx.x;
    const int g   = tid >> 4;        // 16-lane group 0..15
    const int sub = tid & 15;
    const int j0  = sub << 2;        // float4 offset within a row chunk
    const int bf  = blockIdx.x;
    const int b   = bf / NF;
    const int f   = bf - b * NF;
    const int t   = f * HOP + (HOP - 1);

    __shared__ __align__(16) float ash[17];
    __shared__ __align__(16) float y1s[11 * 64];
    __shared__ __align__(16) float y2s[7 * 128];
    __shared__ __align__(16) float y3s[3 * 256];
    __shared__ __align__(16) float in_l[2240];     // overlay: in2(7*320)/in3(3*640)/in4(768)
    __shared__ __align__(16) float zs[512];
    __shared__ __align__(16) float zqs[512];
    __shared__ __align__(16) float rs[64];
    __shared__ float red_d[16];
    __shared__ int   red_i[16];
    __shared__ int   bidx_s;

    // ---- audio window ----
    if (tid < 17) ash[tid] = audio[b * T_IN + (t - 16) + tid];
    __syncthreads();

    // ---- conv1 (1->64, k=7) + elu at 11 positions (tiny) ----
    for (int j = tid; j < 11 * 64; j += 256) {
        const int p = j >> 6, o = j & 63;
        float acc = b1[o];
        #pragma unroll
        for (int k = 0; k < 7; ++k) acc += w1[o * 7 + k] * ash[p + k];
        y1s[p * 64 + o] = elu1(acc);
    }
    __syncthreads();

    // ---- build in2[p*320 + i*5 + k] = y1s[(p+k)*64 + i] ----
    for (int j = tid; j < 7 * 320; j += 256) {
        const int p = j / 320, r = j - p * 320;
        const int i = r / 5, k = r - i * 5;
        in_l[j] = y1s[(p + k) * 64 + i];
    }
    __syncthreads();

    // ---- conv2 (64->128, k=5): 128 ch x 7 pos, row len 320 ----
    {
        float a[7];
        #pragma unroll
        for (int ch = 0; ch < 8; ++ch) {
            const int c = g + (ch << 4);
            const float* wr = w2 + c * 320;
            #pragma unroll
            for (int p = 0; p < 7; ++p) a[p] = 0.f;
            #pragma unroll
            for (int st = 0; st < 5; ++st) {
                const float4 wv = *reinterpret_cast<const float4*>(wr + st * 64 + j0);
                #pragma unroll
                for (int p = 0; p < 7; ++p) {
                    const float4 xv = *reinterpret_cast<const float4*>(&in_l[p * 320 + st * 64 + j0]);
                    a[p] += dot4(wv, xv);
                }
            }
            #pragma unroll
            for (int p = 0; p < 7; ++p) a[p] = red16(a[p]);
            if (sub == 0) {
                #pragma unroll
                for (int p = 0; p < 7; ++p) y2s[p * 128 + c] = elu1(a[p] + b2[c]);
            }
        }
    }
    __syncthreads();

    // ---- build in3[p*640 + i*5 + k] = y2s[(p+k)*128 + i] ----
    for (int j = tid; j < 3 * 640; j += 256) {
        const int p = j / 640, r = j - p * 640;
        const int i = r / 5, k = r - i * 5;
        in_l[j] = y2s[(p + k) * 128 + i];
    }
    __syncthreads();

    // ---- conv3 (128->256, k=5): 256 ch x 3 pos, row len 640 ----
    {
        float a[3];
        #pragma unroll
        for (int ch = 0; ch < 16; ++ch) {
            const int c = g + (ch << 4);
            const float* wr = w3 + c * 640;
            a[0] = a[1] = a[2] = 0.f;
            #pragma unroll
            for (int st = 0; st < 10; ++st) {
                const float4 wv = *reinterpret_cast<const float4*>(wr + st * 64 + j0);
                #pragma unroll
                for (int p = 0; p < 3; ++p) {
                    const float4 xv = *reinterpret_cast<const float4*>(&in_l[p * 640 + st * 64 + j0]);
                    a[p] += dot4(wv, xv);
                }
            }
            #pragma unroll
            for (int p = 0; p < 3; ++p) a[p] = red16(a[p]);
            if (sub == 0) {
                #pragma unroll
                for (int p = 0; p < 3; ++p) y3s[p * 256 + c] = elu1(a[p] + b3[c]);
            }
        }
    }
    __syncthreads();

    // ---- build in4[i*3 + k] = y3s[k*256 + i] ----
    for (int j = tid; j < 768; j += 256) {
        const int i = j / 3, k = j - i * 3;
        in_l[j] = y3s[k * 256 + i];
    }
    __syncthreads();

    // ---- conv4 (256->512, k=3): 512 ch, row len 768 ----
    #pragma unroll
    for (int ch = 0; ch < 32; ++ch) {
        const int c = g + (ch << 4);
        const float* wr = w4 + c * 768;
        float a = 0.f;
        #pragma unroll
        for (int st = 0; st < 12; ++st) {
            const float4 wv = *reinterpret_cast<const float4*>(wr + st * 64 + j0);
            const float4 xv = *reinterpret_cast<const float4*>(&in_l[st * 64 + j0]);
            a += dot4(wv, xv);
        }
        a = red16(a);
        if (sub == 0) zs[c] = elu1(a + b4[c]);
    }
    __syncthreads();

    // ---- RVQ: 8 sequential stages; group g scans codes [g*64, g*64+64) ----
    if (tid < 64) rs[tid] = zs[tid];
    __syncthreads();

    for (int s = 0; s < NCB; ++s) {
        const float* cb = cbs + s * (CBS * CBD);
        const float4 rv = *reinterpret_cast<const float4*>(rs + j0);
        const float rn = red16(dot4(rv, rv));

        float bestd = 3.402823466e38f;
        int   besti = 0;
        const int c0 = g * 64;
        for (int cc = 0; cc < 64; ++cc) {
            const int c = c0 + cc;
            const float4 cv = *reinterpret_cast<const float4*>(cb + c * CBD + j0);
            float dot = red16(dot4(cv, rv));
            float nn;
            if (nrm) {
                nn = nrm[s * CBS + c];
            } else {
                nn = red16(dot4(cv, cv));
            }
            const float d = rn + nn - 2.f * dot;
            if (d < bestd) { bestd = d; besti = c; }   // strict: first min wins
        }
        if (sub == 0) { red_d[g] = bestd; red_i[g] = besti; }
        __syncthreads();
        if (tid == 0) {
            float bd = red_d[0]; int bi = red_i[0];
            #pragma unroll
            for (int q = 1; q < 16; ++q) {
                if (red_d[q] < bd) { bd = red_d[q]; bi = red_i[q]; }
            }
            bidx_s = bi;
            out[b * (NCB * NF) + s * NF + f] = (float)bi;
        }
        __syncthreads();
        const int idx = bidx_s;
        if (g == 0) {
            const float4 q4 = *reinterpret_cast<const float4*>(cb + idx * CBD + j0);
            *reinterpret_cast<float4*>(&zqs[s * 64 + j0]) = q4;
            if (s < NCB - 1) {
                const float4 zn = *reinterpret_cast<const float4*>(&zs[(s + 1) * 64 + j0]);
                float4 nr;
                nr.x = zn.x + (rv.x - q4.x);
                nr.y = zn.y + (rv.y - q4.y);
                nr.z = zn.z + (rv.z - q4.z);
                nr.w = zn.w + (rv.w - q4.w);
                *reinterpret_cast<float4*>(&rs[j0]) = nr;
            }
        }
        __syncthreads();
    }

    // ---- head: 256 outputs (4 heads x 64), row len 512 over zqs ----
    {
        #pragma unroll
        for (int oo = 0; oo < 16; ++oo) {
            const int oc = g + (oo << 4);           // oc = h*64 + o
            const float* wr = hw + oc * 512;
            float a = 0.f;
            #pragma unroll
            for (int st = 0; st < 8; ++st) {
                const float4 wv = *reinterpret_cast<const float4*>(wr + st * 64 + j0);
                const float4 xv = *reinterpret_cast<const float4*>(&zqs[st * 64 + j0]);
                a += dot4(wv, xv);
            }
            a = red16(a);
            if (sub == 0) {
                const int h = oc >> 6, o = oc & 63;
                out[OFF_LOG + ((b * 4 + h) * NF + f) * 64 + o] = a + hb[oc];
            }
        }
    }

    // ---- streaming tails (last frame per batch) ----
    if (f == NF - 1) {
        if (tid < 6) out[OFF_S1 + b * 6 + tid] = audio[b * T_IN + (T_IN - 6) + tid];
        out[OFF_S2 + b * 256 + tid] = y1s[(7 + (tid & 3)) * 64 + (tid >> 2)];
        for (int j = tid; j < 512; j += 256)
            out[OFF_S3 + b * 512 + j] = y2s[(3 + (j & 3)) * 128 + (j >> 2)];
        for (int j = tid; j < 512; j += 256)
            out[OFF_S4 + b * 512 + j] = y3s[(1 + (j & 1)) * 256 + (j >> 1)];
    }
}

extern "C" void kernel_launch(void* const* d_in, const int* in_sizes, int n_in,
                              void* d_out, int out_size, void* d_ws, size_t ws_size,
                              hipStream_t stream) {
    const float* audio = (const float*)d_in[0];
    const float* w1 = (const float*)d_in[1];
    const float* b1 = (const float*)d_in[2];
    const float* w2 = (const float*)d_in[3];
    const float* b2 = (const float*)d_in[4];
    const float* w3 = (const float*)d_in[5];
    const float* b3 = (const float*)d_in[6];
    const float* w4 = (const float*)d_in[7];
    const float* b4 = (const float*)d_in[8];
    const float* cbs = (const float*)d_in[9];
    const float* hw = (const float*)d_in[10];
    const float* hb = (const float*)d_in[11];
    float* out = (float*)d_out;

    float* nrm = nullptr;
    if (ws_size >= (size_t)(NCB * CBS * sizeof(float))) {
        nrm = (float*)d_ws;
        cb_norms_kernel<<<dim3((NCB * CBS) / 16), dim3(256), 0, stream>>>(cbs, nrm);
    }

    enc_fused_kernel<<<dim3(NB * NF), dim3(256), 0, stream>>>(
        audio, w1, b1, w2, b2, w3, b3, w4, b4, cbs, hw, hb, nrm, out);
}

// Round 3
// 516.889 us; speedup vs baseline: 1.6696x; 1.2872x over previous
//
#include <hip/hip_runtime.h>
#include <math.h>

#define HOP   240
#define T_IN  72000
#define NB    4
#define NF    300
#define NCB   8
#define CBS   1024
#define CBD   64

#define OFF_LOG 9600
#define OFF_S1  316800
#define OFF_S2  316824
#define OFF_S3  317848
#define OFF_S4  319896

// workspace layout (float offsets)
#define WS_NRM  0
#define WS_WT2  8192
#define WS_WT3  49152
#define WS_WT4  212992
#define WS_HWT  606208
#define WS_CBT  737280
#define WS_IN2  1261568
#define WS_IN3  3949568
#define WS_IN4  6253568
#define WS_Z    7175168
#define WS_TOTAL 7789568ull   // floats

__device__ __forceinline__ float elu1(float x) { return x > 0.f ? x : expm1f(x); }
__device__ __forceinline__ float dot4(float4 a, float4 b) {
    return a.x * b.x + a.y * b.y + a.z * b.z + a.w * b.w;
}
__device__ __forceinline__ float red16(float v) {
    v += __shfl_xor(v, 1); v += __shfl_xor(v, 2);
    v += __shfl_xor(v, 4); v += __shfl_xor(v, 8);
    return v;
}

// ---------- prep: generic tile transpose dst[k*M+m] = src[m*K+k], M,K mult of 64 ----------
__global__ __launch_bounds__(256)
void transpose_kernel(const float* __restrict__ src0, float* __restrict__ dst0, int M, int K) {
    const float* src = src0 + (size_t)blockIdx.z * M * K;
    float* dst = dst0 + (size_t)blockIdx.z * M * K;
    __shared__ float t[64][65];
    const int k0 = blockIdx.x * 64, m0 = blockIdx.y * 64;
    const int kk = threadIdx.x & 63, q = threadIdx.x >> 6;   // q 0..3
    #pragma unroll
    for (int i = 0; i < 16; ++i) {
        const int m = q * 16 + i;
        t[m][kk] = src[(size_t)(m0 + m) * K + k0 + kk];
    }
    __syncthreads();
    #pragma unroll
    for (int i = 0; i < 16; ++i) {
        const int k = q * 16 + i;
        dst[(size_t)(k0 + k) * M + m0 + kk] = t[kk][k];
    }
}

// ---------- prep: codebook norms ----------
__global__ __launch_bounds__(256)
void cb_norms_kernel(const float* __restrict__ cbs, float* __restrict__ nrm) {
    const int g = threadIdx.x >> 4, sub = threadIdx.x & 15;
    const int code = blockIdx.x * 16 + g;
    const float4 v = *reinterpret_cast<const float4*>(cbs + code * CBD + (sub << 2));
    float s = red16(v.x * v.x + v.y * v.y + v.z * v.z + v.w * v.w);
    if (sub == 0) nrm[code] = s;
}

// ---------- conv1 (1->64, k=7) at 11 positions; writes in2 layout + tails ----------
__global__ __launch_bounds__(64)
void conv1_kernel(const float* __restrict__ audio,
                  const float* __restrict__ w1, const float* __restrict__ b1,
                  float* __restrict__ wsf, float* __restrict__ out)
{
    const int gf = blockIdx.x;
    const int b = gf / NF, f = gf - b * NF;
    const int t = f * HOP + (HOP - 1);
    const int o = threadIdx.x;
    __shared__ float ash[17];
    if (o < 17) ash[o] = audio[b * T_IN + (t - 16) + o];
    __syncthreads();

    float wv[7];
    #pragma unroll
    for (int k = 0; k < 7; ++k) wv[k] = w1[o * 7 + k];
    const float bias = b1[o];
    float y1r[11];
    #pragma unroll
    for (int p = 0; p < 11; ++p) {
        float a = bias;
        #pragma unroll
        for (int k = 0; k < 7; ++k) a += wv[k] * ash[p + k];
        y1r[p] = elu1(a);
    }
    float* in2 = wsf + WS_IN2 + (size_t)gf * 2240;
    #pragma unroll
    for (int p = 0; p < 7; ++p)
        #pragma unroll
        for (int k = 0; k < 5; ++k)
            in2[p * 320 + o * 5 + k] = y1r[p + k];

    if (f == NF - 1) {
        #pragma unroll
        for (int j = 0; j < 4; ++j)
            out[OFF_S2 + b * 256 + o * 4 + j] = y1r[7 + j];
        if (o < 6) out[OFF_S1 + b * 6 + o] = audio[b * T_IN + (T_IN - 6) + o];
    }
}

// ---------- conv2 (64->128, k=5), 5 frames x 7 pos per block ----------
__global__ __launch_bounds__(256)
void conv2_kernel(float* __restrict__ wsf, const float* __restrict__ b2,
                  float* __restrict__ out)
{
    const int blk = blockIdx.x, b = blk / 60, ft = blk - b * 60;
    const int gf0 = b * NF + ft * 5;
    const int c = threadIdx.x & 127, h = threadIdx.x >> 7;
    const float* wT2 = wsf + WS_WT2;
    const float* in2 = wsf + WS_IN2;
    float* in3 = wsf + WS_IN3;

    float acc[5][7];
    #pragma unroll
    for (int f = 0; f < 5; ++f)
        #pragma unroll
        for (int p = 0; p < 7; ++p) acc[f][p] = 0.f;

    const float* wcol = wT2 + c;
    for (int rc = 0; rc < 40; ++rc) {
        const int r = h * 160 + (rc << 2);
        const float w0 = wcol[(r + 0) * 128];
        const float w1v = wcol[(r + 1) * 128];
        const float w2v = wcol[(r + 2) * 128];
        const float w3v = wcol[(r + 3) * 128];
        #pragma unroll
        for (int f = 0; f < 5; ++f) {
            const float4* xr = (const float4*)(in2 + (size_t)(gf0 + f) * 2240);
            #pragma unroll
            for (int p = 0; p < 7; ++p) {
                const float4 xv = xr[(p * 320 + r) >> 2];
                acc[f][p] += w0 * xv.x + w1v * xv.y + w2v * xv.z + w3v * xv.w;
            }
        }
    }

    __shared__ float red[128][35];
    if (h == 1) {
        #pragma unroll
        for (int f = 0; f < 5; ++f)
            #pragma unroll
            for (int p = 0; p < 7; ++p) red[c][f * 7 + p] = acc[f][p];
    }
    __syncthreads();
    if (h == 0) {
        const float bias = b2[c];
        #pragma unroll
        for (int f = 0; f < 5; ++f) {
            const int gf = gf0 + f;
            float* d = in3 + (size_t)gf * 1920;
            #pragma unroll
            for (int p = 0; p < 7; ++p) {
                const float v = elu1(acc[f][p] + red[c][f * 7 + p] + bias);
                const int p2min = p > 4 ? p - 4 : 0;
                const int p2max = p < 2 ? p : 2;
                for (int p2 = p2min; p2 <= p2max; ++p2)
                    d[p2 * 640 + c * 5 + (p - p2)] = v;
                if (ft == 59 && f == 4 && p >= 3)
                    out[OFF_S3 + b * 512 + c * 4 + (p - 3)] = v;
            }
        }
    }
}

// ---------- conv3 (128->256, k=5), 5 frames x 3 pos ----------
__global__ __launch_bounds__(256)
void conv3_kernel(float* __restrict__ wsf, const float* __restrict__ b3,
                  float* __restrict__ out)
{
    const int blk = blockIdx.x, b = blk / 60, ft = blk - b * 60;
    const int gf0 = b * NF + ft * 5;
    const int c = threadIdx.x;
    const float* wT3 = wsf + WS_WT3;
    const float* in3 = wsf + WS_IN3;
    float* in4 = wsf + WS_IN4;

    float acc[5][3];
    #pragma unroll
    for (int f = 0; f < 5; ++f) { acc[f][0] = acc[f][1] = acc[f][2] = 0.f; }

    const float* wcol = wT3 + c;
    for (int rc = 0; rc < 160; ++rc) {
        const int r = rc << 2;
        const float w0 = wcol[(r + 0) * 256];
        const float w1v = wcol[(r + 1) * 256];
        const float w2v = wcol[(r + 2) * 256];
        const float w3v = wcol[(r + 3) * 256];
        #pragma unroll
        for (int f = 0; f < 5; ++f) {
            const float4* xr = (const float4*)(in3 + (size_t)(gf0 + f) * 1920);
            #pragma unroll
            for (int p = 0; p < 3; ++p) {
                const float4 xv = xr[(p * 640 + r) >> 2];
                acc[f][p] += w0 * xv.x + w1v * xv.y + w2v * xv.z + w3v * xv.w;
            }
        }
    }
    const float bias = b3[c];
    #pragma unroll
    for (int f = 0; f < 5; ++f) {
        const int gf = gf0 + f;
        #pragma unroll
        for (int p = 0; p < 3; ++p) {
            const float v = elu1(acc[f][p] + bias);
            in4[(size_t)gf * 768 + c * 3 + p] = v;
            if (ft == 59 && f == 4 && p >= 1)
                out[OFF_S4 + b * 512 + c * 2 + (p - 1)] = v;
        }
    }
}

// ---------- conv4 (256->512, k=3), 5 frames ----------
__global__ __launch_bounds__(256)
void conv4_kernel(float* __restrict__ wsf, const float* __restrict__ b4)
{
    const int blk = blockIdx.x, b = blk / 60, ft = blk - b * 60;
    const int gf0 = b * NF + ft * 5;
    const int c0 = threadIdx.x, c1 = threadIdx.x + 256;
    const float* wT4 = wsf + WS_WT4;
    const float* in4 = wsf + WS_IN4;
    float* zws = wsf + WS_Z;

    float acc0[5], acc1[5];
    #pragma unroll
    for (int f = 0; f < 5; ++f) { acc0[f] = 0.f; acc1[f] = 0.f; }

    for (int rc = 0; rc < 192; ++rc) {
        const int r = rc << 2;
        const float a0 = wT4[(r + 0) * 512 + c0];
        const float a1 = wT4[(r + 1) * 512 + c0];
        const float a2 = wT4[(r + 2) * 512 + c0];
        const float a3 = wT4[(r + 3) * 512 + c0];
        const float d0 = wT4[(r + 0) * 512 + c1];
        const float d1 = wT4[(r + 1) * 512 + c1];
        const float d2 = wT4[(r + 2) * 512 + c1];
        const float d3 = wT4[(r + 3) * 512 + c1];
        #pragma unroll
        for (int f = 0; f < 5; ++f) {
            const float4 xv = ((const float4*)(in4 + (size_t)(gf0 + f) * 768))[rc];
            acc0[f] += a0 * xv.x + a1 * xv.y + a2 * xv.z + a3 * xv.w;
            acc1[f] += d0 * xv.x + d1 * xv.y + d2 * xv.z + d3 * xv.w;
        }
    }
    const float bias0 = b4[c0], bias1 = b4[c1];
    #pragma unroll
    for (int f = 0; f < 5; ++f) {
        zws[(size_t)(gf0 + f) * 512 + c0] = elu1(acc0[f] + bias0);
        zws[(size_t)(gf0 + f) * 512 + c1] = elu1(acc1[f] + bias1);
    }
}

// ---------- RVQ (8 stages) + head, 5 frames per block ----------
__global__ __launch_bounds__(256)
void rvq_head_kernel(float* __restrict__ wsf,
                     const float* __restrict__ cbs,
                     const float* __restrict__ hb,
                     float* __restrict__ out)
{
    const int blk = blockIdx.x, b = blk / 60, ft = blk - b * 60;
    const int gf0 = b * NF + ft * 5;
    const int tid = threadIdx.x;
    const int t4 = tid << 2;
    const float* cbT = wsf + WS_CBT;
    const float* nrm = wsf + WS_NRM;
    const float* hwT = wsf + WS_HWT;
    const float* zws = wsf + WS_Z;

    __shared__ __align__(16) float rs[5 * 64];
    __shared__ __align__(16) float zq[5 * 512];
    __shared__ float redd[5 * 256];
    __shared__ int   redi[5 * 256];
    __shared__ float red2d[5 * 32];
    __shared__ int   red2i[5 * 32];
    __shared__ int   bidx[5];

    for (int u = tid; u < 320; u += 256) {
        const int f = u >> 6, j = u & 63;
        rs[u] = zws[(size_t)(gf0 + f) * 512 + j];
    }
    __syncthreads();

    for (int s = 0; s < NCB; ++s) {
        const float* cbt = cbT + s * (CBS * CBD);
        float dot[4][5];
        float rn[5];
        #pragma unroll
        for (int k = 0; k < 4; ++k)
            #pragma unroll
            for (int f = 0; f < 5; ++f) dot[k][f] = 0.f;
        #pragma unroll
        for (int f = 0; f < 5; ++f) rn[f] = 0.f;

        for (int dc = 0; dc < 16; ++dc) {
            const int d = dc << 2;
            const float4 l0 = *(const float4*)(cbt + (d + 0) * 1024 + t4);
            const float4 l1 = *(const float4*)(cbt + (d + 1) * 1024 + t4);
            const float4 l2 = *(const float4*)(cbt + (d + 2) * 1024 + t4);
            const float4 l3 = *(const float4*)(cbt + (d + 3) * 1024 + t4);
            #pragma unroll
            for (int f = 0; f < 5; ++f) {
                const float4 rv = *(const float4*)&rs[f * 64 + d];
                rn[f] += dot4(rv, rv);
                dot[0][f] += l0.x * rv.x + l1.x * rv.y + l2.x * rv.z + l3.x * rv.w;
                dot[1][f] += l0.y * rv.x + l1.y * rv.y + l2.y * rv.z + l3.y * rv.w;
                dot[2][f] += l0.z * rv.x + l1.z * rv.y + l2.z * rv.z + l3.z * rv.w;
                dot[3][f] += l0.w * rv.x + l1.w * rv.y + l2.w * rv.z + l3.w * rv.w;
            }
        }
        const float4 nn4 = *(const float4*)(nrm + s * CBS + t4);
        #pragma unroll
        for (int f = 0; f < 5; ++f) {
            float bd = rn[f] + nn4.x - 2.f * dot[0][f];
            int bi = t4;
            float dd = rn[f] + nn4.y - 2.f * dot[1][f];
            if (dd < bd) { bd = dd; bi = t4 + 1; }
            dd = rn[f] + nn4.z - 2.f * dot[2][f];
            if (dd < bd) { bd = dd; bi = t4 + 2; }
            dd = rn[f] + nn4.w - 2.f * dot[3][f];
            if (dd < bd) { bd = dd; bi = t4 + 3; }
            redd[f * 256 + tid] = bd;
            redi[f * 256 + tid] = bi;
        }
        __syncthreads();
        if (tid < 160) {
            const int f = tid >> 5, j = tid & 31;
            const int base = f * 256 + j * 8;
            float bd = redd[base]; int bi = redi[base];
            #pragma unroll
            for (int q = 1; q < 8; ++q) {
                const float dd = redd[base + q];
                if (dd < bd) { bd = dd; bi = redi[base + q]; }
            }
            red2d[f * 32 + j] = bd; red2i[f * 32 + j] = bi;
        }
        __syncthreads();
        if (tid < 5) {
            const int f = tid, base = f * 32;
            float bd = red2d[base]; int bi = red2i[base];
            for (int q = 1; q < 32; ++q) {
                const float dd = red2d[base + q];
                if (dd < bd) { bd = dd; bi = red2i[base + q]; }
            }
            bidx[f] = bi;
            out[b * (NCB * NF) + s * NF + (ft * 5 + f)] = (float)bi;
        }
        __syncthreads();
        for (int u = tid; u < 320; u += 256) {
            const int f = u >> 6, j = u & 63;
            const int idx = bidx[f];
            const float q = cbs[(size_t)(s * CBS + idx) * CBD + j];
            zq[f * 512 + s * 64 + j] = q;
            if (s < NCB - 1)
                rs[u] = zws[(size_t)(gf0 + f) * 512 + (s + 1) * 64 + j] + (rs[u] - q);
        }
        __syncthreads();
    }

    // head GEMV: 256 outputs (4 heads x 64), K=512 over zq
    {
        const int oc = tid;
        const float* wcol = hwT + oc;
        float acc[5];
        #pragma unroll
        for (int f = 0; f < 5; ++f) acc[f] = 0.f;
        for (int rc = 0; rc < 128; ++rc) {
            const int r = rc << 2;
            const float w0 = wcol[(r + 0) * 256];
            const float w1v = wcol[(r + 1) * 256];
            const float w2v = wcol[(r + 2) * 256];
            const float w3v = wcol[(r + 3) * 256];
            #pragma unroll
            for (int f = 0; f < 5; ++f) {
                const float4 xv = *(const float4*)&zq[f * 512 + r];
                acc[f] += w0 * xv.x + w1v * xv.y + w2v * xv.z + w3v * xv.w;
            }
        }
        const int h = oc >> 6, o = oc & 63;
        const float bias = hb[oc];
        #pragma unroll
        for (int f = 0; f < 5; ++f)
            out[OFF_LOG + ((size_t)(b * 4 + h) * NF + (ft * 5 + f)) * 64 + o] = acc[f] + bias;
    }
}

// ================= fallback (round-2 fused kernel, used if ws too small) =================
__global__ __launch_bounds__(256)
void enc_fused_kernel(const float* __restrict__ audio,
                      const float* __restrict__ w1, const float* __restrict__ b1,
                      const float* __restrict__ w2, const float* __restrict__ b2,
                      const float* __restrict__ w3, const float* __restrict__ b3,
                      const float* __restrict__ w4, const float* __restrict__ b4,
                      const float* __restrict__ cbs,
                      const float* __restrict__ hw, const float* __restrict__ hb,
                      float* __restrict__ out)
{
    const int tid = threadIdx.x;
    const int g = tid >> 4, sub = tid & 15, j0 = sub << 2;
    const int bf = blockIdx.x, b = bf / NF, f = bf - b * NF;
    const int t = f * HOP + (HOP - 1);

    __shared__ __align__(16) float ash[17];
    __shared__ __align__(16) float y1s[11 * 64];
    __shared__ __align__(16) float y2s[7 * 128];
    __shared__ __align__(16) float y3s[3 * 256];
    __shared__ __align__(16) float in_l[2240];
    __shared__ __align__(16) float zs[512];
    __shared__ __align__(16) float zqs[512];
    __shared__ __align__(16) float rsl[64];
    __shared__ float rdd[16]; __shared__ int rdi[16]; __shared__ int bidx_s;

    if (tid < 17) ash[tid] = audio[b * T_IN + (t - 16) + tid];
    __syncthreads();
    for (int j = tid; j < 11 * 64; j += 256) {
        const int p = j >> 6, o = j & 63;
        float acc = b1[o];
        for (int k = 0; k < 7; ++k) acc += w1[o * 7 + k] * ash[p + k];
        y1s[p * 64 + o] = elu1(acc);
    }
    __syncthreads();
    for (int j = tid; j < 7 * 320; j += 256) {
        const int p = j / 320, r = j - p * 320, i = r / 5, k = r - i * 5;
        in_l[j] = y1s[(p + k) * 64 + i];
    }
    __syncthreads();
    {
        float a[7];
        for (int ch = 0; ch < 8; ++ch) {
            const int c = g + (ch << 4);
            const float* wr = w2 + c * 320;
            for (int p = 0; p < 7; ++p) a[p] = 0.f;
            for (int st = 0; st < 5; ++st) {
                const float4 wv = *(const float4*)(wr + st * 64 + j0);
                for (int p = 0; p < 7; ++p)
                    a[p] += dot4(wv, *(const float4*)&in_l[p * 320 + st * 64 + j0]);
            }
            for (int p = 0; p < 7; ++p) a[p] = red16(a[p]);
            if (sub == 0) for (int p = 0; p < 7; ++p) y2s[p * 128 + c] = elu1(a[p] + b2[c]);
        }
    }
    __syncthreads();
    for (int j = tid; j < 3 * 640; j += 256) {
        const int p = j / 640, r = j - p * 640, i = r / 5, k = r - i * 5;
        in_l[j] = y2s[(p + k) * 128 + i];
    }
    __syncthreads();
    {
        float a[3];
        for (int ch = 0; ch < 16; ++ch) {
            const int c = g + (ch << 4);
            const float* wr = w3 + c * 640;
            a[0] = a[1] = a[2] = 0.f;
            for (int st = 0; st < 10; ++st) {
                const float4 wv = *(const float4*)(wr + st * 64 + j0);
                for (int p = 0; p < 3; ++p)
                    a[p] += dot4(wv, *(const float4*)&in_l[p * 640 + st * 64 + j0]);
            }
            for (int p = 0; p < 3; ++p) a[p] = red16(a[p]);
            if (sub == 0) for (int p = 0; p < 3; ++p) y3s[p * 256 + c] = elu1(a[p] + b3[c]);
        }
    }
    __syncthreads();
    for (int j = tid; j < 768; j += 256) { const int i = j / 3, k = j - i * 3; in_l[j] = y3s[k * 256 + i]; }
    __syncthreads();
    for (int ch = 0; ch < 32; ++ch) {
        const int c = g + (ch << 4);
        const float* wr = w4 + c * 768;
        float a = 0.f;
        for (int st = 0; st < 12; ++st)
            a += dot4(*(const float4*)(wr + st * 64 + j0), *(const float4*)&in_l[st * 64 + j0]);
        a = red16(a);
        if (sub == 0) zs[c] = elu1(a + b4[c]);
    }
    __syncthreads();
    if (tid < 64) rsl[tid] = zs[tid];
    __syncthreads();
    for (int s = 0; s < NCB; ++s) {
        const float* cb = cbs + s * (CBS * CBD);
        const float4 rv = *(const float4*)(rsl + j0);
        const float rn = red16(dot4(rv, rv));
        float bestd = 3.402823466e38f; int besti = 0;
        const int c0 = g * 64;
        for (int cc = 0; cc < 64; ++cc) {
            const int c = c0 + cc;
            const float4 cv = *(const float4*)(cb + c * CBD + j0);
            const float dt = red16(dot4(cv, rv));
            const float nn = red16(dot4(cv, cv));
            const float d = rn + nn - 2.f * dt;
            if (d < bestd) { bestd = d; besti = c; }
        }
        if (sub == 0) { rdd[g] = bestd; rdi[g] = besti; }
        __syncthreads();
        if (tid == 0) {
            float bd = rdd[0]; int bi = rdi[0];
            for (int q = 1; q < 16; ++q) if (rdd[q] < bd) { bd = rdd[q]; bi = rdi[q]; }
            bidx_s = bi;
            out[b * (NCB * NF) + s * NF + f] = (float)bi;
        }
        __syncthreads();
        const int idx = bidx_s;
        if (g == 0) {
            const float4 q4 = *(const float4*)(cb + idx * CBD + j0);
            *(float4*)&zqs[s * 64 + j0] = q4;
            if (s < NCB - 1) {
                const float4 zn = *(const float4*)&zs[(s + 1) * 64 + j0];
                float4 nr;
                nr.x = zn.x + (rv.x - q4.x); nr.y = zn.y + (rv.y - q4.y);
                nr.z = zn.z + (rv.z - q4.z); nr.w = zn.w + (rv.w - q4.w);
                *(float4*)&rsl[j0] = nr;
            }
        }
        __syncthreads();
    }
    for (int oo = 0; oo < 16; ++oo) {
        const int oc = g + (oo << 4);
        const float* wr = hw + oc * 512;
        float a = 0.f;
        for (int st = 0; st < 8; ++st)
            a += dot4(*(const float4*)(wr + st * 64 + j0), *(const float4*)&zqs[st * 64 + j0]);
        a = red16(a);
        if (sub == 0) {
            const int h = oc >> 6, o = oc & 63;
            out[OFF_LOG + ((b * 4 + h) * NF + f) * 64 + o] = a + hb[oc];
        }
    }
    if (f == NF - 1) {
        if (tid < 6) out[OFF_S1 + b * 6 + tid] = audio[b * T_IN + (T_IN - 6) + tid];
        out[OFF_S2 + b * 256 + tid] = y1s[(7 + (tid & 3)) * 64 + (tid >> 2)];
        for (int j = tid; j < 512; j += 256)
            out[OFF_S3 + b * 512 + j] = y2s[(3 + (j & 3)) * 128 + (j >> 2)];
        for (int j = tid; j < 512; j += 256)
            out[OFF_S4 + b * 512 + j] = y3s[(1 + (j & 1)) * 256 + (j >> 1)];
    }
}

extern "C" void kernel_launch(void* const* d_in, const int* in_sizes, int n_in,
                              void* d_out, int out_size, void* d_ws, size_t ws_size,
                              hipStream_t stream) {
    const float* audio = (const float*)d_in[0];
    const float* w1 = (const float*)d_in[1];
    const float* b1 = (const float*)d_in[2];
    const float* w2 = (const float*)d_in[3];
    const float* b2 = (const float*)d_in[4];
    const float* w3 = (const float*)d_in[5];
    const float* b3 = (const float*)d_in[6];
    const float* w4 = (const float*)d_in[7];
    const float* b4 = (const float*)d_in[8];
    const float* cbs = (const float*)d_in[9];
    const float* hw = (const float*)d_in[10];
    const float* hb = (const float*)d_in[11];
    float* out = (float*)d_out;
    float* wsf = (float*)d_ws;

    if (ws_size >= WS_TOTAL * sizeof(float)) {
        // prep: transposes + norms
        transpose_kernel<<<dim3(5, 2, 1), 256, 0, stream>>>(w2, wsf + WS_WT2, 128, 320);
        transpose_kernel<<<dim3(10, 4, 1), 256, 0, stream>>>(w3, wsf + WS_WT3, 256, 640);
        transpose_kernel<<<dim3(12, 8, 1), 256, 0, stream>>>(w4, wsf + WS_WT4, 512, 768);
        transpose_kernel<<<dim3(8, 4, 1), 256, 0, stream>>>(hw, wsf + WS_HWT, 256, 512);
        transpose_kernel<<<dim3(1, 16, 8), 256, 0, stream>>>(cbs, wsf + WS_CBT, 1024, 64);
        cb_norms_kernel<<<dim3(512), 256, 0, stream>>>(cbs, wsf + WS_NRM);
        // pipeline
        conv1_kernel<<<dim3(NB * NF), 64, 0, stream>>>(audio, w1, b1, wsf, out);
        conv2_kernel<<<dim3(240), 256, 0, stream>>>(wsf, b2, out);
        conv3_kernel<<<dim3(240), 256, 0, stream>>>(wsf, b3, out);
        conv4_kernel<<<dim3(240), 256, 0, stream>>>(wsf, b4);
        rvq_head_kernel<<<dim3(240), 256, 0, stream>>>(wsf, cbs, hb, out);
    } else {
        enc_fused_kernel<<<dim3(NB * NF), 256, 0, stream>>>(
            audio, w1, b1, w2, b2, w3, b3, w4, b4, cbs, hw, hb, out);
    }
}

// Round 4
// 312.771 us; speedup vs baseline: 2.7592x; 1.6526x over previous
//
#include <hip/hip_runtime.h>
#include <math.h>

#define HOP   240
#define T_IN  72000
#define NB    4
#define NF    300
#define NCB   8
#define CBS   1024
#define CBD   64

#define OFF_LOG 9600
#define OFF_S1  316800
#define OFF_S2  316824
#define OFF_S3  317848
#define OFF_S4  319896

// workspace layout (float offsets)
#define WS_NRM  0          // 8192
#define WS_WT2  8192       // 40960  (320x128)
#define WS_WT3  49152      // 163840 (640x256)
#define WS_WT4  212992     // 393216 (768x512)
#define WS_HWT  606208     // 131072 (512x256)
#define WS_CBT  737280     // 524288 (8 x 64x1024)
#define WS_IN3  1261568    // 1200*1920
#define WS_IN4  3565568    // 1200*768
#define WS_Z    4487168    // 1200*512
#define WS_TOTAL 5101568ull

__device__ __forceinline__ float elu1(float x) { return x > 0.f ? x : expm1f(x); }
__device__ __forceinline__ float dot4(float4 a, float4 b) {
    return a.x * b.x + a.y * b.y + a.z * b.z + a.w * b.w;
}
__device__ __forceinline__ float red16(float v) {
    v += __shfl_xor(v, 1); v += __shfl_xor(v, 2);
    v += __shfl_xor(v, 4); v += __shfl_xor(v, 8);
    return v;
}

// ---------- prep: tile transpose dst[k*M+m] = src[m*K+k], M,K mult of 64 ----------
__global__ __launch_bounds__(256)
void transpose_kernel(const float* __restrict__ src0, float* __restrict__ dst0, int M, int K) {
    const float* src = src0 + (size_t)blockIdx.z * M * K;
    float* dst = dst0 + (size_t)blockIdx.z * M * K;
    __shared__ float t[64][65];
    const int k0 = blockIdx.x * 64, m0 = blockIdx.y * 64;
    const int kk = threadIdx.x & 63, q = threadIdx.x >> 6;
    #pragma unroll
    for (int i = 0; i < 16; ++i) {
        const int m = q * 16 + i;
        t[m][kk] = src[(size_t)(m0 + m) * K + k0 + kk];
    }
    __syncthreads();
    #pragma unroll
    for (int i = 0; i < 16; ++i) {
        const int k = q * 16 + i;
        dst[(size_t)(k0 + k) * M + m0 + kk] = t[kk][k];
    }
}

// ---------- prep: codebook norms ----------
__global__ __launch_bounds__(256)
void cb_norms_kernel(const float* __restrict__ cbs, float* __restrict__ nrm) {
    const int g = threadIdx.x >> 4, sub = threadIdx.x & 15;
    const int code = blockIdx.x * 16 + g;
    const float4 v = *reinterpret_cast<const float4*>(cbs + code * CBD + (sub << 2));
    float s = red16(v.x * v.x + v.y * v.y + v.z * v.z + v.w * v.w);
    if (sub == 0) nrm[code] = s;
}

// ---------- conv1+conv2 fused, 1 frame per block (G=1200, 256 thr) ----------
__global__ __launch_bounds__(256)
void conv12_kernel(const float* __restrict__ audio,
                   const float* __restrict__ w1, const float* __restrict__ b1,
                   const float* __restrict__ b2,
                   float* __restrict__ wsf, float* __restrict__ out)
{
    const int gf = blockIdx.x;
    const int b = gf / NF, f = gf - b * NF;
    const int t = f * HOP + (HOP - 1);
    const int tid = threadIdx.x;

    __shared__ float ash[17];
    __shared__ __align__(16) float in2L[2240];   // [p(7)][i*5+k] (320)
    __shared__ float redL[128][7];

    if (tid < 17) ash[tid] = audio[b * T_IN + (t - 16) + tid];
    __syncthreads();

    if (tid < 64) {
        const int o = tid;
        float wv[7];
        #pragma unroll
        for (int k = 0; k < 7; ++k) wv[k] = w1[o * 7 + k];
        const float bias = b1[o];
        float y1r[11];
        #pragma unroll
        for (int p = 0; p < 11; ++p) {
            float a = bias;
            #pragma unroll
            for (int k = 0; k < 7; ++k) a += wv[k] * ash[p + k];
            y1r[p] = elu1(a);
        }
        #pragma unroll
        for (int p = 0; p < 7; ++p)
            #pragma unroll
            for (int k = 0; k < 5; ++k)
                in2L[p * 320 + o * 5 + k] = y1r[p + k];
        if (f == NF - 1) {
            #pragma unroll
            for (int j = 0; j < 4; ++j)
                out[OFF_S2 + b * 256 + o * 4 + j] = y1r[7 + j];
            if (o < 6) out[OFF_S1 + b * 6 + o] = audio[b * T_IN + (T_IN - 6) + o];
        }
    }
    __syncthreads();

    // conv2: 128 ch x 2 K-halves (K=160 each), 7 positions
    const int c = tid & 127, h = tid >> 7;
    const float* wcol = wsf + WS_WT2 + (size_t)(h * 160) * 128 + c;
    float acc[7];
    #pragma unroll
    for (int p = 0; p < 7; ++p) acc[p] = 0.f;
    for (int rc = 0; rc < 40; ++rc) {
        const int r = rc << 2;
        const float w0 = wcol[(r + 0) * 128];
        const float w1v = wcol[(r + 1) * 128];
        const float w2v = wcol[(r + 2) * 128];
        const float w3v = wcol[(r + 3) * 128];
        #pragma unroll
        for (int p = 0; p < 7; ++p) {
            const float4 xv = *(const float4*)&in2L[p * 320 + h * 160 + r];
            acc[p] += w0 * xv.x + w1v * xv.y + w2v * xv.z + w3v * xv.w;
        }
    }
    if (h == 1) {
        #pragma unroll
        for (int p = 0; p < 7; ++p) redL[c][p] = acc[p];
    }
    __syncthreads();
    if (h == 0) {
        const float bias = b2[c];
        float* d = wsf + WS_IN3 + (size_t)gf * 1920;
        #pragma unroll
        for (int p = 0; p < 7; ++p) {
            const float v = elu1(acc[p] + redL[c][p] + bias);
            const int p2min = p > 4 ? p - 4 : 0;
            const int p2max = p < 2 ? p : 2;
            for (int p2 = p2min; p2 <= p2max; ++p2)
                d[p2 * 640 + c * 5 + (p - p2)] = v;
            if (f == NF - 1 && p >= 3)
                out[OFF_S3 + b * 512 + c * 4 + (p - 3)] = v;
        }
    }
}

// ---------- conv3 (128->256 k=5): 4 frames x channel-half per block (G=600) ----------
__global__ __launch_bounds__(256)
void conv3_kernel(const float* __restrict__ b3, float* __restrict__ wsf,
                  float* __restrict__ out)
{
    const int blk = blockIdx.x;
    const int fg = blk >> 1, chalf = blk & 1;
    const int gf0 = fg * 4;
    const int b = gf0 / NF;
    const int tid = threadIdx.x;
    const int c128 = tid & 127, h = tid >> 7;
    const int c = chalf * 128 + c128;

    __shared__ __align__(16) float xs[4 * 1920];
    __shared__ float redL[128][12];

    const float4* in3 = (const float4*)(wsf + WS_IN3 + (size_t)gf0 * 1920);
    for (int j = tid; j < 1920; j += 256)
        *(float4*)&xs[j << 2] = in3[j];
    __syncthreads();

    const float* wcol = wsf + WS_WT3 + (size_t)(h * 320) * 256 + c;
    float acc[4][3];
    #pragma unroll
    for (int ff = 0; ff < 4; ++ff) { acc[ff][0] = acc[ff][1] = acc[ff][2] = 0.f; }
    for (int rc = 0; rc < 80; ++rc) {
        const int r = rc << 2;
        const float w0 = wcol[(r + 0) * 256];
        const float w1v = wcol[(r + 1) * 256];
        const float w2v = wcol[(r + 2) * 256];
        const float w3v = wcol[(r + 3) * 256];
        #pragma unroll
        for (int ff = 0; ff < 4; ++ff)
            #pragma unroll
            for (int p = 0; p < 3; ++p) {
                const float4 xv = *(const float4*)&xs[ff * 1920 + p * 640 + h * 320 + r];
                acc[ff][p] += w0 * xv.x + w1v * xv.y + w2v * xv.z + w3v * xv.w;
            }
    }
    if (h == 1) {
        #pragma unroll
        for (int ff = 0; ff < 4; ++ff)
            #pragma unroll
            for (int p = 0; p < 3; ++p) redL[c128][ff * 3 + p] = acc[ff][p];
    }
    __syncthreads();
    if (h == 0) {
        const float bias = b3[c];
        #pragma unroll
        for (int ff = 0; ff < 4; ++ff) {
            const int gf = gf0 + ff;
            #pragma unroll
            for (int p = 0; p < 3; ++p) {
                const float v = elu1(acc[ff][p] + redL[c128][ff * 3 + p] + bias);
                wsf[WS_IN4 + (size_t)gf * 768 + c * 3 + p] = v;
                if (gf == NB * NF - 1 && p >= 1)
                    out[OFF_S4 + b * 512 + c * 2 + (p - 1)] = v;
            }
        }
    }
}

// ---------- conv4 (256->512 k=3): 4 frames x channel-half per block (G=600) ----------
__global__ __launch_bounds__(256)
void conv4_kernel(const float* __restrict__ b4, float* __restrict__ wsf)
{
    const int blk = blockIdx.x;
    const int fg = blk >> 1, chalf = blk & 1;
    const int gf0 = fg * 4;
    const int tid = threadIdx.x;
    const int c = chalf * 256 + tid;

    __shared__ __align__(16) float xs[4 * 768];
    const float4* in4 = (const float4*)(wsf + WS_IN4 + (size_t)gf0 * 768);
    for (int j = tid; j < 768; j += 256)
        *(float4*)&xs[j << 2] = in4[j];
    __syncthreads();

    const float* wcol = wsf + WS_WT4 + c;
    float acc[4] = {0.f, 0.f, 0.f, 0.f};
    for (int rc = 0; rc < 192; ++rc) {
        const int r = rc << 2;
        const float w0 = wcol[(size_t)(r + 0) * 512];
        const float w1v = wcol[(size_t)(r + 1) * 512];
        const float w2v = wcol[(size_t)(r + 2) * 512];
        const float w3v = wcol[(size_t)(r + 3) * 512];
        #pragma unroll
        for (int ff = 0; ff < 4; ++ff) {
            const float4 xv = *(const float4*)&xs[ff * 768 + r];
            acc[ff] += w0 * xv.x + w1v * xv.y + w2v * xv.z + w3v * xv.w;
        }
    }
    const float bias = b4[c];
    #pragma unroll
    for (int ff = 0; ff < 4; ++ff)
        wsf[WS_Z + (size_t)(gf0 + ff) * 512 + c] = elu1(acc[ff] + bias);
}

// ---------- RVQ (8 stages) + head: 5 frames per block, 512 threads (G=240) ----------
__global__ __launch_bounds__(512)
void rvq_head_kernel(const float* __restrict__ cbs,
                     const float* __restrict__ hb,
                     float* __restrict__ wsf, float* __restrict__ out)
{
    const int blk = blockIdx.x;          // 0..239
    const int gf0 = blk * 5;
    const int b = gf0 / NF;
    const int f0 = gf0 - b * NF;
    const int tid = threadIdx.x;

    const float* cbT = wsf + WS_CBT;
    const float* nrm = wsf + WS_NRM;
    const float* hwT = wsf + WS_HWT;
    const float* zws = wsf + WS_Z;

    __shared__ __align__(16) float rs[5 * 64];
    __shared__ __align__(16) float zq[5 * 512];
    __shared__ float redd[5 * 512];
    __shared__ int   redi[5 * 512];
    __shared__ float red2d[5 * 64];
    __shared__ int   red2i[5 * 64];
    __shared__ int   bidx[5];

    for (int u = tid; u < 320; u += 512) {
        const int ff = u >> 6, j = u & 63;
        rs[u] = zws[(size_t)(gf0 + ff) * 512 + j];
    }
    __syncthreads();

    const int c0 = tid << 1;             // this thread's 2 codes
    for (int s = 0; s < NCB; ++s) {
        const float* cbt = cbT + s * (CBS * CBD);
        float dA[5], dB[5], rn[5];
        #pragma unroll
        for (int ff = 0; ff < 5; ++ff) { dA[ff] = 0.f; dB[ff] = 0.f; rn[ff] = 0.f; }

        for (int dc = 0; dc < 16; ++dc) {
            const int d = dc << 2;
            const float2 l0 = *(const float2*)(cbt + (size_t)(d + 0) * 1024 + c0);
            const float2 l1 = *(const float2*)(cbt + (size_t)(d + 1) * 1024 + c0);
            const float2 l2 = *(const float2*)(cbt + (size_t)(d + 2) * 1024 + c0);
            const float2 l3 = *(const float2*)(cbt + (size_t)(d + 3) * 1024 + c0);
            #pragma unroll
            for (int ff = 0; ff < 5; ++ff) {
                const float4 rv = *(const float4*)&rs[ff * 64 + d];
                rn[ff] += dot4(rv, rv);
                dA[ff] += l0.x * rv.x + l1.x * rv.y + l2.x * rv.z + l3.x * rv.w;
                dB[ff] += l0.y * rv.x + l1.y * rv.y + l2.y * rv.z + l3.y * rv.w;
            }
        }
        const float2 nn = *(const float2*)(nrm + s * CBS + c0);
        #pragma unroll
        for (int ff = 0; ff < 5; ++ff) {
            float bd = rn[ff] + nn.x - 2.f * dA[ff];
            int bi = c0;
            const float dd = rn[ff] + nn.y - 2.f * dB[ff];
            if (dd < bd) { bd = dd; bi = c0 + 1; }
            redd[ff * 512 + tid] = bd;
            redi[ff * 512 + tid] = bi;
        }
        __syncthreads();
        if (tid < 320) {
            const int ff = tid >> 6, j = tid & 63;
            float bd = redd[ff * 512 + j];
            int bi = redi[ff * 512 + j];
            #pragma unroll
            for (int q = 1; q < 8; ++q) {
                const float dd = redd[ff * 512 + j + (q << 6)];
                if (dd < bd) { bd = dd; bi = redi[ff * 512 + j + (q << 6)]; }
            }
            red2d[ff * 64 + j] = bd;
            red2i[ff * 64 + j] = bi;
        }
        __syncthreads();
        if (tid < 5) {
            float bd = red2d[tid * 64];
            int bi = red2i[tid * 64];
            for (int q = 1; q < 64; ++q) {
                const float dd = red2d[tid * 64 + q];
                if (dd < bd) { bd = dd; bi = red2i[tid * 64 + q]; }
            }
            bidx[tid] = bi;
            out[b * (NCB * NF) + s * NF + (f0 + tid)] = (float)bi;
        }
        __syncthreads();
        for (int u = tid; u < 320; u += 512) {
            const int ff = u >> 6, j = u & 63;
            const int idx = bidx[ff];
            const float q = cbs[(size_t)(s * CBS + idx) * CBD + j];
            zq[ff * 512 + s * 64 + j] = q;
            if (s < NCB - 1)
                rs[u] = zws[(size_t)(gf0 + ff) * 512 + (s + 1) * 64 + j] + (rs[u] - q);
        }
        __syncthreads();
    }

    // head GEMV: 256 outputs x 5 frames, K=512 split across wave-halves
    {
        const int oc = tid & 255, h = tid >> 8;
        const float* wcol = hwT + (size_t)(h * 256) * 256 + oc;
        float acc[5];
        #pragma unroll
        for (int ff = 0; ff < 5; ++ff) acc[ff] = 0.f;
        for (int rc = 0; rc < 64; ++rc) {
            const int r = rc << 2;
            const float w0 = wcol[(r + 0) * 256];
            const float w1v = wcol[(r + 1) * 256];
            const float w2v = wcol[(r + 2) * 256];
            const float w3v = wcol[(r + 3) * 256];
            #pragma unroll
            for (int ff = 0; ff < 5; ++ff) {
                const float4 xv = *(const float4*)&zq[ff * 512 + h * 256 + r];
                acc[ff] += w0 * xv.x + w1v * xv.y + w2v * xv.z + w3v * xv.w;
            }
        }
        if (h == 1) {
            #pragma unroll
            for (int ff = 0; ff < 5; ++ff) redd[oc * 5 + ff] = acc[ff];
        }
        __syncthreads();
        if (h == 0) {
            const float bias = hb[oc];
            const int hh = oc >> 6, o = oc & 63;
            #pragma unroll
            for (int ff = 0; ff < 5; ++ff)
                out[OFF_LOG + ((size_t)(b * 4 + hh) * NF + (f0 + ff)) * 64 + o]
                    = acc[ff] + redd[oc * 5 + ff] + bias;
        }
    }
}

// ================= fallback (round-2 fused kernel, used if ws too small) =================
__global__ __launch_bounds__(256)
void enc_fused_kernel(const float* __restrict__ audio,
                      const float* __restrict__ w1, const float* __restrict__ b1,
                      const float* __restrict__ w2, const float* __restrict__ b2,
                      const float* __restrict__ w3, const float* __restrict__ b3,
                      const float* __restrict__ w4, const float* __restrict__ b4,
                      const float* __restrict__ cbs,
                      const float* __restrict__ hw, const float* __restrict__ hb,
                      float* __restrict__ out)
{
    const int tid = threadIdx.x;
    const int g = tid >> 4, sub = tid & 15, j0 = sub << 2;
    const int bf = blockIdx.x, b = bf / NF, f = bf - b * NF;
    const int t = f * HOP + (HOP - 1);

    __shared__ __align__(16) float ash[17];
    __shared__ __align__(16) float y1s[11 * 64];
    __shared__ __align__(16) float y2s[7 * 128];
    __shared__ __align__(16) float y3s[3 * 256];
    __shared__ __align__(16) float in_l[2240];
    __shared__ __align__(16) float zs[512];
    __shared__ __align__(16) float zqs[512];
    __shared__ __align__(16) float rsl[64];
    __shared__ float rdd[16]; __shared__ int rdi[16]; __shared__ int bidx_s;

    if (tid < 17) ash[tid] = audio[b * T_IN + (t - 16) + tid];
    __syncthreads();
    for (int j = tid; j < 11 * 64; j += 256) {
        const int p = j >> 6, o = j & 63;
        float acc = b1[o];
        for (int k = 0; k < 7; ++k) acc += w1[o * 7 + k] * ash[p + k];
        y1s[p * 64 + o] = elu1(acc);
    }
    __syncthreads();
    for (int j = tid; j < 7 * 320; j += 256) {
        const int p = j / 320, r = j - p * 320, i = r / 5, k = r - i * 5;
        in_l[j] = y1s[(p + k) * 64 + i];
    }
    __syncthreads();
    {
        float a[7];
        for (int ch = 0; ch < 8; ++ch) {
            const int c = g + (ch << 4);
            const float* wr = w2 + c * 320;
            for (int p = 0; p < 7; ++p) a[p] = 0.f;
            for (int st = 0; st < 5; ++st) {
                const float4 wv = *(const float4*)(wr + st * 64 + j0);
                for (int p = 0; p < 7; ++p)
                    a[p] += dot4(wv, *(const float4*)&in_l[p * 320 + st * 64 + j0]);
            }
            for (int p = 0; p < 7; ++p) a[p] = red16(a[p]);
            if (sub == 0) for (int p = 0; p < 7; ++p) y2s[p * 128 + c] = elu1(a[p] + b2[c]);
        }
    }
    __syncthreads();
    for (int j = tid; j < 3 * 640; j += 256) {
        const int p = j / 640, r = j - p * 640, i = r / 5, k = r - i * 5;
        in_l[j] = y2s[(p + k) * 128 + i];
    }
    __syncthreads();
    {
        float a[3];
        for (int ch = 0; ch < 16; ++ch) {
            const int c = g + (ch << 4);
            const float* wr = w3 + c * 640;
            a[0] = a[1] = a[2] = 0.f;
            for (int st = 0; st < 10; ++st) {
                const float4 wv = *(const float4*)(wr + st * 64 + j0);
                for (int p = 0; p < 3; ++p)
                    a[p] += dot4(wv, *(const float4*)&in_l[p * 640 + st * 64 + j0]);
            }
            for (int p = 0; p < 3; ++p) a[p] = red16(a[p]);
            if (sub == 0) for (int p = 0; p < 3; ++p) y3s[p * 256 + c] = elu1(a[p] + b3[c]);
        }
    }
    __syncthreads();
    for (int j = tid; j < 768; j += 256) { const int i = j / 3, k = j - i * 3; in_l[j] = y3s[k * 256 + i]; }
    __syncthreads();
    for (int ch = 0; ch < 32; ++ch) {
        const int c = g + (ch << 4);
        const float* wr = w4 + c * 768;
        float a = 0.f;
        for (int st = 0; st < 12; ++st)
            a += dot4(*(const float4*)(wr + st * 64 + j0), *(const float4*)&in_l[st * 64 + j0]);
        a = red16(a);
        if (sub == 0) zs[c] = elu1(a + b4[c]);
    }
    __syncthreads();
    if (tid < 64) rsl[tid] = zs[tid];
    __syncthreads();
    for (int s = 0; s < NCB; ++s) {
        const float* cb = cbs + s * (CBS * CBD);
        const float4 rv = *(const float4*)(rsl + j0);
        const float rn = red16(dot4(rv, rv));
        float bestd = 3.402823466e38f; int besti = 0;
        const int c0 = g * 64;
        for (int cc = 0; cc < 64; ++cc) {
            const int c = c0 + cc;
            const float4 cv = *(const float4*)(cb + c * CBD + j0);
            const float dt = red16(dot4(cv, rv));
            const float nn = red16(dot4(cv, cv));
            const float d = rn + nn - 2.f * dt;
            if (d < bestd) { bestd = d; besti = c; }
        }
        if (sub == 0) { rdd[g] = bestd; rdi[g] = besti; }
        __syncthreads();
        if (tid == 0) {
            float bd = rdd[0]; int bi = rdi[0];
            for (int q = 1; q < 16; ++q) if (rdd[q] < bd) { bd = rdd[q]; bi = rdi[q]; }
            bidx_s = bi;
            out[b * (NCB * NF) + s * NF + f] = (float)bi;
        }
        __syncthreads();
        const int idx = bidx_s;
        if (g == 0) {
            const float4 q4 = *(const float4*)(cb + idx * CBD + j0);
            *(float4*)&zqs[s * 64 + j0] = q4;
            if (s < NCB - 1) {
                const float4 zn = *(const float4*)&zs[(s + 1) * 64 + j0];
                float4 nr;
                nr.x = zn.x + (rv.x - q4.x); nr.y = zn.y + (rv.y - q4.y);
                nr.z = zn.z + (rv.z - q4.z); nr.w = zn.w + (rv.w - q4.w);
                *(float4*)&rsl[j0] = nr;
            }
        }
        __syncthreads();
    }
    for (int oo = 0; oo < 16; ++oo) {
        const int oc = g + (oo << 4);
        const float* wr = hw + oc * 512;
        float a = 0.f;
        for (int st = 0; st < 8; ++st)
            a += dot4(*(const float4*)(wr + st * 64 + j0), *(const float4*)&zqs[st * 64 + j0]);
        a = red16(a);
        if (sub == 0) {
            const int h = oc >> 6, o = oc & 63;
            out[OFF_LOG + ((b * 4 + h) * NF + f) * 64 + o] = a + hb[oc];
        }
    }
    if (f == NF - 1) {
        if (tid < 6) out[OFF_S1 + b * 6 + tid] = audio[b * T_IN + (T_IN - 6) + tid];
        out[OFF_S2 + b * 256 + tid] = y1s[(7 + (tid & 3)) * 64 + (tid >> 2)];
        for (int j = tid; j < 512; j += 256)
            out[OFF_S3 + b * 512 + j] = y2s[(3 + (j & 3)) * 128 + (j >> 2)];
        for (int j = tid; j < 512; j += 256)
            out[OFF_S4 + b * 512 + j] = y3s[(1 + (j & 1)) * 256 + (j >> 1)];
    }
}

extern "C" void kernel_launch(void* const* d_in, const int* in_sizes, int n_in,
                              void* d_out, int out_size, void* d_ws, size_t ws_size,
                              hipStream_t stream) {
    const float* audio = (const float*)d_in[0];
    const float* w1 = (const float*)d_in[1];
    const float* b1 = (const float*)d_in[2];
    const float* w2 = (const float*)d_in[3];
    const float* b2 = (const float*)d_in[4];
    const float* w3 = (const float*)d_in[5];
    const float* b3 = (const float*)d_in[6];
    const float* w4 = (const float*)d_in[7];
    const float* b4 = (const float*)d_in[8];
    const float* cbs = (const float*)d_in[9];
    const float* hw = (const float*)d_in[10];
    const float* hb = (const float*)d_in[11];
    float* out = (float*)d_out;
    float* wsf = (float*)d_ws;

    if (ws_size >= WS_TOTAL * sizeof(float)) {
        transpose_kernel<<<dim3(5, 2, 1), 256, 0, stream>>>(w2, wsf + WS_WT2, 128, 320);
        transpose_kernel<<<dim3(10, 4, 1), 256, 0, stream>>>(w3, wsf + WS_WT3, 256, 640);
        transpose_kernel<<<dim3(12, 8, 1), 256, 0, stream>>>(w4, wsf + WS_WT4, 512, 768);
        transpose_kernel<<<dim3(8, 4, 1), 256, 0, stream>>>(hw, wsf + WS_HWT, 256, 512);
        transpose_kernel<<<dim3(1, 16, 8), 256, 0, stream>>>(cbs, wsf + WS_CBT, 1024, 64);
        cb_norms_kernel<<<dim3(512), 256, 0, stream>>>(cbs, wsf + WS_NRM);

        conv12_kernel<<<dim3(NB * NF), 256, 0, stream>>>(audio, w1, b1, b2, wsf, out);
        conv3_kernel<<<dim3(600), 256, 0, stream>>>(b3, wsf, out);
        conv4_kernel<<<dim3(600), 256, 0, stream>>>(b4, wsf);
        rvq_head_kernel<<<dim3(240), 512, 0, stream>>>(cbs, hb, wsf, out);
    } else {
        enc_fused_kernel<<<dim3(NB * NF), 256, 0, stream>>>(
            audio, w1, b1, w2, b2, w3, b3, w4, b4, cbs, hw, hb, out);
    }
}

// Round 5
// 295.660 us; speedup vs baseline: 2.9189x; 1.0579x over previous
//
#include <hip/hip_runtime.h>
#include <math.h>

#define HOP   240
#define T_IN  72000
#define NB    4
#define NF    300
#define NCB   8
#define CBS   1024
#define CBD   64

#define OFF_LOG 9600
#define OFF_S1  316800
#define OFF_S2  316824
#define OFF_S3  317848
#define OFF_S4  319896

// workspace layout (float offsets)
#define WS_NRM  0          // 8192
#define WS_W2P  8192       // 320*128  = 40960
#define WS_W3P  49152      // 640*256  = 163840
#define WS_W4P  212992     // 768*512  = 393216
#define WS_HWT  606208     // 512*256  = 131072
#define WS_CBT  737280     // 8*64*1024 = 524288
#define WS_IN3  1261568    // 1200*896 = 1075200   y2 compact [gf][p*128+c], p<7
#define WS_IN4  2336768    // 1200*768 = 921600    y3 compact [gf][p*256+c], p<3
#define WS_Z    3258368    // 1200*512 = 614400
#define WS_TOTAL 3872768ull

__device__ __forceinline__ float elu1(float x) { return x > 0.f ? x : expm1f(x); }
__device__ __forceinline__ float dot4(float4 a, float4 b) {
    return a.x * b.x + a.y * b.y + a.z * b.z + a.w * b.w;
}
__device__ __forceinline__ float red16(float v) {
    v += __shfl_xor(v, 1); v += __shfl_xor(v, 2);
    v += __shfl_xor(v, 4); v += __shfl_xor(v, 8);
    return v;
}
// monotone float->uint map (ascending float order -> ascending uint order)
__device__ __forceinline__ unsigned int fkey(float f) {
    unsigned int u = __float_as_uint(f);
    return (u & 0x80000000u) ? ~u : (u | 0x80000000u);
}

// ---------- ONE prep kernel: permuted weight transposes + cb transpose + norms ----------
// dst[(perm(col))*C + c] = src[c*L + col];  perm(col) = (K==1) ? col : (col%K)*I + col/K
__global__ __launch_bounds__(256)
void prep_kernel(const float* __restrict__ w2, const float* __restrict__ w3,
                 const float* __restrict__ w4, const float* __restrict__ hw,
                 const float* __restrict__ cbs, float* __restrict__ wsf)
{
    const int bid = blockIdx.x;
    const float* src; float* dst;
    int R, L, I, K, tix, cx;
    bool do_norm = false;
    float* nrmp = nullptr;
    if (bid < 10)       { src = w2; dst = wsf + WS_W2P; R = 128; L = 320; I = 64;  K = 5; tix = bid;       cx = 5;  }
    else if (bid < 50)  { src = w3; dst = wsf + WS_W3P; R = 256; L = 640; I = 128; K = 5; tix = bid - 10;  cx = 10; }
    else if (bid < 146) { src = w4; dst = wsf + WS_W4P; R = 512; L = 768; I = 256; K = 3; tix = bid - 50;  cx = 12; }
    else if (bid < 178) { src = hw; dst = wsf + WS_HWT; R = 256; L = 512; I = 512; K = 1; tix = bid - 146; cx = 8;  }
    else {
        const int e = bid - 178, book = e >> 4;
        src = cbs + (size_t)book * 65536; dst = wsf + WS_CBT + (size_t)book * 65536;
        R = 1024; L = 64; I = 64; K = 1; tix = e & 15; cx = 1;
        do_norm = true; nrmp = wsf + WS_NRM + book * 1024;
    }
    const int c0 = (tix % cx) * 64, r0 = (tix / cx) * 64;
    const int lane = threadIdx.x & 63, q = threadIdx.x >> 6;

    __shared__ float tS[64][65];
    __shared__ float npart[4][64];

    #pragma unroll
    for (int i = 0; i < 16; ++i) {
        const int rr = q * 16 + i;
        tS[rr][lane] = src[(size_t)(r0 + rr) * L + c0 + lane];
    }
    __syncthreads();

    if (do_norm) {
        float s = 0.f;
        #pragma unroll
        for (int j = 0; j < 16; ++j) { const float v = tS[lane][q * 16 + j]; s += v * v; }
        npart[q][lane] = s;
        __syncthreads();
        if (threadIdx.x < 64)
            nrmp[r0 + threadIdx.x] = npart[0][threadIdx.x] + npart[1][threadIdx.x]
                                   + npart[2][threadIdx.x] + npart[3][threadIdx.x];
    }

    #pragma unroll
    for (int i = 0; i < 16; ++i) {
        const int col = c0 + q * 16 + i;
        const int dr = (K == 1) ? col : (col % K) * I + col / K;
        dst[(size_t)dr * R + r0 + lane] = tS[lane][q * 16 + i];
    }
}

// ---------- conv1+conv2 fused, 1 frame per block (G=1200, 256 thr) ----------
__global__ __launch_bounds__(256)
void conv12_kernel(const float* __restrict__ audio,
                   const float* __restrict__ w1, const float* __restrict__ b1,
                   const float* __restrict__ b2,
                   float* __restrict__ wsf, float* __restrict__ out)
{
    const int gf = blockIdx.x;
    const int b = gf / NF, f = gf - b * NF;
    const int t = f * HOP + (HOP - 1);
    const int tid = threadIdx.x;

    __shared__ float ash[17];
    __shared__ __align__(16) float y1c[704];     // [p(11)][o(64)] compact
    __shared__ float redL[7][128];

    if (tid < 17) ash[tid] = audio[b * T_IN + (t - 16) + tid];
    __syncthreads();

    if (tid < 64) {
        const int o = tid;
        float wv[7];
        #pragma unroll
        for (int k = 0; k < 7; ++k) wv[k] = w1[o * 7 + k];
        const float bias = b1[o];
        float y1r[11];
        #pragma unroll
        for (int p = 0; p < 11; ++p) {
            float a = bias;
            #pragma unroll
            for (int k = 0; k < 7; ++k) a += wv[k] * ash[p + k];
            y1r[p] = elu1(a);
            y1c[p * 64 + o] = y1r[p];
        }
        if (f == NF - 1) {
            #pragma unroll
            for (int j = 0; j < 4; ++j)
                out[OFF_S2 + b * 256 + o * 4 + j] = y1r[7 + j];
            if (o < 6) out[OFF_S1 + b * 6 + o] = audio[b * T_IN + (T_IN - 6) + o];
        }
    }
    __syncthreads();

    // conv2: window for pos p is y1c[p*64 .. p*64+320); K split 2x160
    const int c = tid & 127, h = tid >> 7;
    const float* wbase = wsf + WS_W2P + (size_t)(h * 160) * 128 + c;
    float acc[7];
    #pragma unroll
    for (int p = 0; p < 7; ++p) acc[p] = 0.f;
    for (int rc = 0; rc < 40; ++rc) {
        const int r = rc << 2;
        const float w0 = wbase[(r + 0) * 128];
        const float w1v = wbase[(r + 1) * 128];
        const float w2v = wbase[(r + 2) * 128];
        const float w3v = wbase[(r + 3) * 128];
        #pragma unroll
        for (int p = 0; p < 7; ++p) {
            const float4 xv = *(const float4*)&y1c[p * 64 + h * 160 + r];
            acc[p] += w0 * xv.x + w1v * xv.y + w2v * xv.z + w3v * xv.w;
        }
    }
    if (h == 1) {
        #pragma unroll
        for (int p = 0; p < 7; ++p) redL[p][c] = acc[p];
    }
    __syncthreads();
    if (h == 0) {
        const float bias = b2[c];
        #pragma unroll
        for (int p = 0; p < 7; ++p) {
            const float v = elu1(acc[p] + redL[p][c] + bias);
            wsf[WS_IN3 + (size_t)gf * 896 + p * 128 + c] = v;
            if (f == NF - 1 && p >= 3)
                out[OFF_S3 + b * 512 + c * 4 + (p - 3)] = v;
        }
    }
}

// ---------- conv3 (128->256 k=5): F=4, 512 thr = 256c x 2 K-halves (G=300) ----------
__global__ __launch_bounds__(512)
void conv3_kernel(const float* __restrict__ b3, float* __restrict__ wsf,
                  float* __restrict__ out)
{
    const int gf0 = blockIdx.x * 4;
    const int tid = threadIdx.x;
    const int c = tid & 255, h = tid >> 8;

    __shared__ __align__(16) float xs[4 * 896];
    __shared__ float redL[12][256];

    const float4* srcv = (const float4*)(wsf + WS_IN3 + (size_t)gf0 * 896);
    for (int j = tid; j < 896; j += 512) ((float4*)xs)[j] = srcv[j];
    __syncthreads();

    const float* wbase = wsf + WS_W3P + (size_t)(h * 320) * 256 + c;
    float acc[4][3];
    #pragma unroll
    for (int ff = 0; ff < 4; ++ff) { acc[ff][0] = acc[ff][1] = acc[ff][2] = 0.f; }
    for (int rc = 0; rc < 80; ++rc) {
        const int r = rc << 2;
        const float w0 = wbase[(r + 0) * 256];
        const float w1v = wbase[(r + 1) * 256];
        const float w2v = wbase[(r + 2) * 256];
        const float w3v = wbase[(r + 3) * 256];
        #pragma unroll
        for (int ff = 0; ff < 4; ++ff)
            #pragma unroll
            for (int p = 0; p < 3; ++p) {
                const float4 xv = *(const float4*)&xs[ff * 896 + p * 128 + h * 320 + r];
                acc[ff][p] += w0 * xv.x + w1v * xv.y + w2v * xv.z + w3v * xv.w;
            }
    }
    if (h == 1) {
        #pragma unroll
        for (int ff = 0; ff < 4; ++ff)
            #pragma unroll
            for (int p = 0; p < 3; ++p) redL[ff * 3 + p][c] = acc[ff][p];
    }
    __syncthreads();
    if (h == 0) {
        const float bias = b3[c];
        #pragma unroll
        for (int ff = 0; ff < 4; ++ff) {
            const int gf = gf0 + ff;
            #pragma unroll
            for (int p = 0; p < 3; ++p) {
                const float v = elu1(acc[ff][p] + redL[ff * 3 + p][c] + bias);
                wsf[WS_IN4 + (size_t)gf * 768 + p * 256 + c] = v;
                if ((gf % NF) == NF - 1 && p >= 1)
                    out[OFF_S4 + (gf / NF) * 512 + c * 2 + (p - 1)] = v;
            }
        }
    }
}

// ---------- conv4 (256->512 k=3): F=4, 512 thr = 512 channels (G=300) ----------
__global__ __launch_bounds__(512)
void conv4_kernel(const float* __restrict__ b4, float* __restrict__ wsf)
{
    const int gf0 = blockIdx.x * 4;
    const int tid = threadIdx.x;
    const int c = tid;

    __shared__ __align__(16) float xs[4 * 768];
    const float4* srcv = (const float4*)(wsf + WS_IN4 + (size_t)gf0 * 768);
    for (int j = tid; j < 768; j += 512) ((float4*)xs)[j] = srcv[j];
    __syncthreads();

    const float* wcol = wsf + WS_W4P + c;
    float acc[4] = {0.f, 0.f, 0.f, 0.f};
    for (int rc = 0; rc < 192; ++rc) {
        const int r = rc << 2;
        const float w0 = wcol[(size_t)(r + 0) * 512];
        const float w1v = wcol[(size_t)(r + 1) * 512];
        const float w2v = wcol[(size_t)(r + 2) * 512];
        const float w3v = wcol[(size_t)(r + 3) * 512];
        #pragma unroll
        for (int ff = 0; ff < 4; ++ff) {
            const float4 xv = *(const float4*)&xs[ff * 768 + r];
            acc[ff] += w0 * xv.x + w1v * xv.y + w2v * xv.z + w3v * xv.w;
        }
    }
    const float bias = b4[c];
    #pragma unroll
    for (int ff = 0; ff < 4; ++ff)
        wsf[WS_Z + (size_t)(gf0 + ff) * 512 + c] = elu1(acc[ff] + bias);
}

// ---------- RVQ (8 stages) + head: 5 frames, 512 thr (G=240) ----------
__global__ __launch_bounds__(512)
void rvq_head_kernel(const float* __restrict__ cbs,
                     const float* __restrict__ hb,
                     float* __restrict__ wsf, float* __restrict__ out)
{
    const int blk = blockIdx.x;
    const int gf0 = blk * 5;
    const int b = gf0 / NF;
    const int f0 = gf0 - b * NF;
    const int tid = threadIdx.x;
    const int lane = tid & 63, wid = tid >> 6;

    const float* cbT = wsf + WS_CBT;
    const float* nrm = wsf + WS_NRM;
    const float* hwT = wsf + WS_HWT;
    const float* zws = wsf + WS_Z;

    __shared__ __align__(16) float zsL[2560];
    __shared__ __align__(16) float rs[320];
    __shared__ __align__(16) float zq[2560];
    __shared__ float rnS[5];
    __shared__ unsigned long long mk[2][5];
    __shared__ float hpart[1280];

    for (int u = tid; u < 2560; u += 512) zsL[u] = zws[(size_t)gf0 * 512 + u];
    if (tid < 10) mk[tid / 5][tid % 5] = ~0ull;
    __syncthreads();

    if (tid < 320) {
        const float v = zsL[wid * 512 + lane];
        rs[tid] = v;
        float ss = v * v;
        #pragma unroll
        for (int m = 1; m < 64; m <<= 1) ss += __shfl_xor(ss, m);
        if (lane == 0) rnS[wid] = ss;
    }
    __syncthreads();

    const int c0 = tid << 1;
    for (int s = 0; s < NCB; ++s) {
        const float* cbt = cbT + (size_t)s * 65536;
        float dA[5], dB[5];
        #pragma unroll
        for (int ff = 0; ff < 5; ++ff) { dA[ff] = 0.f; dB[ff] = 0.f; }

        for (int dc = 0; dc < 16; ++dc) {
            const int d = dc << 2;
            const float2 l0 = *(const float2*)(cbt + (size_t)(d + 0) * 1024 + c0);
            const float2 l1 = *(const float2*)(cbt + (size_t)(d + 1) * 1024 + c0);
            const float2 l2 = *(const float2*)(cbt + (size_t)(d + 2) * 1024 + c0);
            const float2 l3 = *(const float2*)(cbt + (size_t)(d + 3) * 1024 + c0);
            #pragma unroll
            for (int ff = 0; ff < 5; ++ff) {
                const float4 rv = *(const float4*)&rs[ff * 64 + d];
                dA[ff] += l0.x * rv.x + l1.x * rv.y + l2.x * rv.z + l3.x * rv.w;
                dB[ff] += l0.y * rv.x + l1.y * rv.y + l2.y * rv.z + l3.y * rv.w;
            }
        }
        const float2 nn = *(const float2*)(nrm + s * CBS + c0);
        unsigned long long key[5];
        #pragma unroll
        for (int ff = 0; ff < 5; ++ff) {
            const float rn = rnS[ff];
            const float da = (rn + nn.x) - 2.f * dA[ff];
            const float db = (rn + nn.y) - 2.f * dB[ff];
            const unsigned long long ka = ((unsigned long long)fkey(da) << 32) | (unsigned)c0;
            const unsigned long long kb = ((unsigned long long)fkey(db) << 32) | (unsigned)(c0 + 1);
            key[ff] = ka < kb ? ka : kb;
        }
        #pragma unroll
        for (int m = 1; m < 64; m <<= 1) {
            #pragma unroll
            for (int ff = 0; ff < 5; ++ff) {
                const unsigned long long o = __shfl_xor(key[ff], m);
                if (o < key[ff]) key[ff] = o;
            }
        }
        if (lane == 0) {
            #pragma unroll
            for (int ff = 0; ff < 5; ++ff)
                atomicMin(&mk[s & 1][ff], key[ff]);
        }
        __syncthreads();

        if (tid < 5)
            out[b * (NCB * NF) + s * NF + (f0 + tid)]
                = (float)(unsigned)(mk[s & 1][tid] & 0xFFFFFFFFull);
        if (tid < 320) {
            const int idx = (int)(unsigned)(mk[s & 1][wid] & 0xFFFFFFFFull);
            const float q = cbs[(size_t)(s * CBS + idx) * CBD + lane];
            zq[wid * 512 + s * 64 + lane] = q;
            if (s < NCB - 1) {
                const float nr = zsL[wid * 512 + (s + 1) * 64 + lane] + (rs[tid] - q);
                rs[tid] = nr;
                float ss = nr * nr;
                #pragma unroll
                for (int m = 1; m < 64; m <<= 1) ss += __shfl_xor(ss, m);
                if (lane == 0) rnS[wid] = ss;
            }
        }
        if (tid >= 320 && tid < 325) mk[(s + 1) & 1][tid - 320] = ~0ull;
        __syncthreads();
    }

    // head GEMV: 256 outputs x 5 frames, K=512 split across thread-halves
    {
        const int oc = tid & 255, h = tid >> 8;
        const float* wcol = hwT + (size_t)(h * 256) * 256 + oc;
        float acc[5];
        #pragma unroll
        for (int ff = 0; ff < 5; ++ff) acc[ff] = 0.f;
        for (int rc = 0; rc < 64; ++rc) {
            const int r = rc << 2;
            const float w0 = wcol[(r + 0) * 256];
            const float w1v = wcol[(r + 1) * 256];
            const float w2v = wcol[(r + 2) * 256];
            const float w3v = wcol[(r + 3) * 256];
            #pragma unroll
            for (int ff = 0; ff < 5; ++ff) {
                const float4 xv = *(const float4*)&zq[ff * 512 + h * 256 + r];
                acc[ff] += w0 * xv.x + w1v * xv.y + w2v * xv.z + w3v * xv.w;
            }
        }
        if (h == 1) {
            #pragma unroll
            for (int ff = 0; ff < 5; ++ff) hpart[oc * 5 + ff] = acc[ff];
        }
        __syncthreads();
        if (h == 0) {
            const float bias = hb[oc];
            const int hh = oc >> 6, o = oc & 63;
            #pragma unroll
            for (int ff = 0; ff < 5; ++ff)
                out[OFF_LOG + ((size_t)(b * 4 + hh) * NF + (f0 + ff)) * 64 + o]
                    = acc[ff] + hpart[oc * 5 + ff] + bias;
        }
    }
}

// ================= fallback (round-2 fused kernel, used if ws too small) =================
__global__ __launch_bounds__(256)
void enc_fused_kernel(const float* __restrict__ audio,
                      const float* __restrict__ w1, const float* __restrict__ b1,
                      const float* __restrict__ w2, const float* __restrict__ b2,
                      const float* __restrict__ w3, const float* __restrict__ b3,
                      const float* __restrict__ w4, const float* __restrict__ b4,
                      const float* __restrict__ cbs,
                      const float* __restrict__ hw, const float* __restrict__ hb,
                      float* __restrict__ out)
{
    const int tid = threadIdx.x;
    const int g = tid >> 4, sub = tid & 15, j0 = sub << 2;
    const int bf = blockIdx.x, b = bf / NF, f = bf - b * NF;
    const int t = f * HOP + (HOP - 1);

    __shared__ __align__(16) float ash[17];
    __shared__ __align__(16) float y1s[11 * 64];
    __shared__ __align__(16) float y2s[7 * 128];
    __shared__ __align__(16) float y3s[3 * 256];
    __shared__ __align__(16) float in_l[2240];
    __shared__ __align__(16) float zs[512];
    __shared__ __align__(16) float zqs[512];
    __shared__ __align__(16) float rsl[64];
    __shared__ float rdd[16]; __shared__ int rdi[16]; __shared__ int bidx_s;

    if (tid < 17) ash[tid] = audio[b * T_IN + (t - 16) + tid];
    __syncthreads();
    for (int j = tid; j < 11 * 64; j += 256) {
        const int p = j >> 6, o = j & 63;
        float acc = b1[o];
        for (int k = 0; k < 7; ++k) acc += w1[o * 7 + k] * ash[p + k];
        y1s[p * 64 + o] = elu1(acc);
    }
    __syncthreads();
    for (int j = tid; j < 7 * 320; j += 256) {
        const int p = j / 320, r = j - p * 320, i = r / 5, k = r - i * 5;
        in_l[j] = y1s[(p + k) * 64 + i];
    }
    __syncthreads();
    {
        float a[7];
        for (int ch = 0; ch < 8; ++ch) {
            const int c = g + (ch << 4);
            const float* wr = w2 + c * 320;
            for (int p = 0; p < 7; ++p) a[p] = 0.f;
            for (int st = 0; st < 5; ++st) {
                const float4 wv = *(const float4*)(wr + st * 64 + j0);
                for (int p = 0; p < 7; ++p)
                    a[p] += dot4(wv, *(const float4*)&in_l[p * 320 + st * 64 + j0]);
            }
            for (int p = 0; p < 7; ++p) a[p] = red16(a[p]);
            if (sub == 0) for (int p = 0; p < 7; ++p) y2s[p * 128 + c] = elu1(a[p] + b2[c]);
        }
    }
    __syncthreads();
    for (int j = tid; j < 3 * 640; j += 256) {
        const int p = j / 640, r = j - p * 640, i = r / 5, k = r - i * 5;
        in_l[j] = y2s[(p + k) * 128 + i];
    }
    __syncthreads();
    {
        float a[3];
        for (int ch = 0; ch < 16; ++ch) {
            const int c = g + (ch << 4);
            const float* wr = w3 + c * 640;
            a[0] = a[1] = a[2] = 0.f;
            for (int st = 0; st < 10; ++st) {
                const float4 wv = *(const float4*)(wr + st * 64 + j0);
                for (int p = 0; p < 3; ++p)
                    a[p] += dot4(wv, *(const float4*)&in_l[p * 640 + st * 64 + j0]);
            }
            for (int p = 0; p < 3; ++p) a[p] = red16(a[p]);
            if (sub == 0) for (int p = 0; p < 3; ++p) y3s[p * 256 + c] = elu1(a[p] + b3[c]);
        }
    }
    __syncthreads();
    for (int j = tid; j < 768; j += 256) { const int i = j / 3, k = j - i * 3; in_l[j] = y3s[k * 256 + i]; }
    __syncthreads();
    for (int ch = 0; ch < 32; ++ch) {
        const int c = g + (ch << 4);
        const float* wr = w4 + c * 768;
        float a = 0.f;
        for (int st = 0; st < 12; ++st)
            a += dot4(*(const float4*)(wr + st * 64 + j0), *(const float4*)&in_l[st * 64 + j0]);
        a = red16(a);
        if (sub == 0) zs[c] = elu1(a + b4[c]);
    }
    __syncthreads();
    if (tid < 64) rsl[tid] = zs[tid];
    __syncthreads();
    for (int s = 0; s < NCB; ++s) {
        const float* cb = cbs + s * (CBS * CBD);
        const float4 rv = *(const float4*)(rsl + j0);
        const float rn = red16(dot4(rv, rv));
        float bestd = 3.402823466e38f; int besti = 0;
        const int c0 = g * 64;
        for (int cc = 0; cc < 64; ++cc) {
            const int c = c0 + cc;
            const float4 cv = *(const float4*)(cb + c * CBD + j0);
            const float dt = red16(dot4(cv, rv));
            const float nnv = red16(dot4(cv, cv));
            const float d = rn + nnv - 2.f * dt;
            if (d < bestd) { bestd = d; besti = c; }
        }
        if (sub == 0) { rdd[g] = bestd; rdi[g] = besti; }
        __syncthreads();
        if (tid == 0) {
            float bd = rdd[0]; int bi = rdi[0];
            for (int q = 1; q < 16; ++q) if (rdd[q] < bd) { bd = rdd[q]; bi = rdi[q]; }
            bidx_s = bi;
            out[b * (NCB * NF) + s * NF + f] = (float)bi;
        }
        __syncthreads();
        const int idx = bidx_s;
        if (g == 0) {
            const float4 q4 = *(const float4*)(cb + idx * CBD + j0);
            *(float4*)&zqs[s * 64 + j0] = q4;
            if (s < NCB - 1) {
                const float4 zn = *(const float4*)&zs[(s + 1) * 64 + j0];
                float4 nr;
                nr.x = zn.x + (rv.x - q4.x); nr.y = zn.y + (rv.y - q4.y);
                nr.z = zn.z + (rv.z - q4.z); nr.w = zn.w + (rv.w - q4.w);
                *(float4*)&rsl[j0] = nr;
            }
        }
        __syncthreads();
    }
    for (int oo = 0; oo < 16; ++oo) {
        const int oc = g + (oo << 4);
        const float* wr = hw + oc * 512;
        float a = 0.f;
        for (int st = 0; st < 8; ++st)
            a += dot4(*(const float4*)(wr + st * 64 + j0), *(const float4*)&zqs[st * 64 + j0]);
        a = red16(a);
        if (sub == 0) {
            const int h = oc >> 6, o = oc & 63;
            out[OFF_LOG + ((b * 4 + h) * NF + f) * 64 + o] = a + hb[oc];
        }
    }
    if (f == NF - 1) {
        if (tid < 6) out[OFF_S1 + b * 6 + tid] = audio[b * T_IN + (T_IN - 6) + tid];
        out[OFF_S2 + b * 256 + tid] = y1s[(7 + (tid & 3)) * 64 + (tid >> 2)];
        for (int j = tid; j < 512; j += 256)
            out[OFF_S3 + b * 512 + j] = y2s[(3 + (j & 3)) * 128 + (j >> 2)];
        for (int j = tid; j < 512; j += 256)
            out[OFF_S4 + b * 512 + j] = y3s[(1 + (j & 1)) * 256 + (j >> 1)];
    }
}

extern "C" void kernel_launch(void* const* d_in, const int* in_sizes, int n_in,
                              void* d_out, int out_size, void* d_ws, size_t ws_size,
                              hipStream_t stream) {
    const float* audio = (const float*)d_in[0];
    const float* w1 = (const float*)d_in[1];
    const float* b1 = (const float*)d_in[2];
    const float* w2 = (const float*)d_in[3];
    const float* b2 = (const float*)d_in[4];
    const float* w3 = (const float*)d_in[5];
    const float* b3 = (const float*)d_in[6];
    const float* w4 = (const float*)d_in[7];
    const float* b4 = (const float*)d_in[8];
    const float* cbs = (const float*)d_in[9];
    const float* hw = (const float*)d_in[10];
    const float* hb = (const float*)d_in[11];
    float* out = (float*)d_out;
    float* wsf = (float*)d_ws;

    if (ws_size >= WS_TOTAL * sizeof(float)) {
        prep_kernel<<<dim3(306), 256, 0, stream>>>(w2, w3, w4, hw, cbs, wsf);
        conv12_kernel<<<dim3(NB * NF), 256, 0, stream>>>(audio, w1, b1, b2, wsf, out);
        conv3_kernel<<<dim3(300), 512, 0, stream>>>(b3, wsf, out);
        conv4_kernel<<<dim3(300), 512, 0, stream>>>(b4, wsf);
        rvq_head_kernel<<<dim3(240), 512, 0, stream>>>(cbs, hb, wsf, out);
    } else {
        enc_fused_kernel<<<dim3(NB * NF), 256, 0, stream>>>(
            audio, w1, b1, w2, b2, w3, b3, w4, b4, cbs, hw, hb, out);
    }
}

// Round 6
// 253.120 us; speedup vs baseline: 3.4095x; 1.1681x over previous
//
#include <hip/hip_runtime.h>
#include <math.h>

#define HOP   240
#define T_IN  72000
#define NB    4
#define NF    300
#define NCB   8
#define CBS   1024
#define CBD   64

#define OFF_LOG 9600
#define OFF_S1  316800
#define OFF_S2  316824
#define OFF_S3  317848
#define OFF_S4  319896

// workspace layout (float offsets) — all packed-float4 forms
#define WS_NRM   0          // 8192
#define WS_W2P4  8192       // 40960   [k*16+it][128c][4i]
#define WS_W3P4  49152      // 163840  [k*32+it][256c][4i]
#define WS_W4P4  212992     // 393216  [k*64+it][512c][4i]
#define WS_HW4   606208     // 131072  [d4][256oc][4d]
#define WS_CBP4  737280     // 524288  [s][d4][1024code][4d]
#define WS_TOTAL 1261568ull // floats

__device__ __forceinline__ float elu1(float x) { return x > 0.f ? x : expm1f(x); }
__device__ __forceinline__ float dot4(float4 a, float4 b) {
    return a.x * b.x + a.y * b.y + a.z * b.z + a.w * b.w;
}
__device__ __forceinline__ float red16(float v) {
    v += __shfl_xor(v, 1); v += __shfl_xor(v, 2);
    v += __shfl_xor(v, 4); v += __shfl_xor(v, 8);
    return v;
}
__device__ __forceinline__ unsigned int fkey(float f) {
    unsigned int u = __float_as_uint(f);
    return (u & 0x80000000u) ? ~u : (u | 0x80000000u);
}

// ---------- prep: packed transposes + codebook norms ----------
// col -> dr = (K==1)? col : (col%K)*I + col/K   (k-major, i-minor)
// packed: dst[((dr/4)*R + c)*4 + dr%4] = src[c*L + col]
__global__ __launch_bounds__(256)
void prep_kernel(const float* __restrict__ w2, const float* __restrict__ w3,
                 const float* __restrict__ w4, const float* __restrict__ hw,
                 const float* __restrict__ cbs, float* __restrict__ wsf)
{
    const int bid = blockIdx.x;
    const float* src; float* dst;
    int R, L, I, K, tix, cx;
    bool do_norm = false;
    float* nrmp = nullptr;
    if (bid < 10)       { src = w2; dst = wsf + WS_W2P4; R = 128; L = 320; I = 64;  K = 5; tix = bid;       cx = 5;  }
    else if (bid < 50)  { src = w3; dst = wsf + WS_W3P4; R = 256; L = 640; I = 128; K = 5; tix = bid - 10;  cx = 10; }
    else if (bid < 146) { src = w4; dst = wsf + WS_W4P4; R = 512; L = 768; I = 256; K = 3; tix = bid - 50;  cx = 12; }
    else if (bid < 178) { src = hw; dst = wsf + WS_HW4;  R = 256; L = 512; I = 512; K = 1; tix = bid - 146; cx = 8;  }
    else {
        const int e = bid - 178, book = e >> 4;
        src = cbs + (size_t)book * 65536; dst = wsf + WS_CBP4 + (size_t)book * 65536;
        R = 1024; L = 64; I = 64; K = 1; tix = e & 15; cx = 1;
        do_norm = true; nrmp = wsf + WS_NRM + book * 1024;
    }
    const int c0 = (tix % cx) * 64, r0 = (tix / cx) * 64;
    const int lane = threadIdx.x & 63, q = threadIdx.x >> 6;

    __shared__ float tS[64][65];
    __shared__ float npart[4][64];

    #pragma unroll
    for (int i = 0; i < 16; ++i) {
        const int rr = q * 16 + i;
        tS[rr][lane] = src[(size_t)(r0 + rr) * L + c0 + lane];
    }
    __syncthreads();

    if (do_norm) {
        float s = 0.f;
        #pragma unroll
        for (int j = 0; j < 16; ++j) { const float v = tS[lane][q * 16 + j]; s += v * v; }
        npart[q][lane] = s;
        __syncthreads();
        if (threadIdx.x < 64)
            nrmp[r0 + threadIdx.x] = npart[0][threadIdx.x] + npart[1][threadIdx.x]
                                   + npart[2][threadIdx.x] + npart[3][threadIdx.x];
    }

    #pragma unroll
    for (int i = 0; i < 16; ++i) {
        const int col = c0 + q * 16 + i;
        const int dr = (K == 1) ? col : (col % K) * I + col / K;
        dst[((size_t)(dr >> 2) * R + (r0 + lane)) * 4 + (dr & 3)] = tS[lane][q * 16 + i];
    }
}

// ---------- mega kernel: conv1..conv4 + RVQ + head, 5 frames/block, G=240 ----------
__global__ __launch_bounds__(512)
void mega_kernel(const float* __restrict__ audio,
                 const float* __restrict__ w1, const float* __restrict__ b1,
                 const float* __restrict__ b2, const float* __restrict__ b3,
                 const float* __restrict__ b4, const float* __restrict__ cbs,
                 const float* __restrict__ hb, const float* __restrict__ wsf,
                 float* __restrict__ out)
{
    const int blk = blockIdx.x;            // 0..239
    const int b   = blk / 60;              // batch
    const int f0  = (blk - b * 60) * 5;    // frame base within batch
    const int tid = threadIdx.x;
    const int lane = tid & 63, wid = tid >> 6;

    __shared__ float ashL[5][18];
    __shared__ __align__(16) float y1L[5 * 704];   // [f][q*64+o], q<11
    __shared__ __align__(16) float y2L[5 * 896];   // [f][q*128+c], q<7
    __shared__ __align__(16) float y3L[5 * 768];   // [f][p*256+c], p<3
    __shared__ __align__(16) float zsL[5 * 512];
    __shared__ __align__(16) float zqL[5 * 512];
    __shared__ __align__(16) float rs[320];
    __shared__ float redL[4480];                   // conv2 [35][128] / conv3 [15][256] / head [256*5]
    __shared__ float rnS[5];
    __shared__ unsigned long long mk[2][5];

    // ================= P0: conv1 (1->64, k=7) at 11 positions, 5 frames =================
    if (tid < 85) {
        const int f = tid / 17, j = tid - (tid / 17) * 17;
        ashL[f][j] = audio[b * T_IN + (f0 + f) * HOP + 223 + j];
    }
    if (blk == 239 && tid < 6) out[OFF_S1 + 3 * 6 + tid] = audio[3 * T_IN + (T_IN - 6) + tid];
    __syncthreads();

    if (tid < 320) {
        const int f = tid >> 6, o = tid & 63;
        float wv[7];
        #pragma unroll
        for (int k = 0; k < 7; ++k) wv[k] = w1[o * 7 + k];
        const float bias = b1[o];
        float y1r[11];
        #pragma unroll
        for (int p = 0; p < 11; ++p) {
            float a = bias;
            #pragma unroll
            for (int k = 0; k < 7; ++k) a += wv[k] * ashL[f][p + k];
            y1r[p] = elu1(a);
            y1L[f * 704 + p * 64 + o] = y1r[p];
        }
        if (blk == 239 && f == 4) {
            #pragma unroll
            for (int j = 0; j < 4; ++j) out[OFF_S2 + 3 * 256 + o * 4 + j] = y1r[7 + j];
        }
    }
    __syncthreads();

    // ================= P1: conv2 (64->128, k=5), 7 positions =================
    // threads: c=tid&127, h=(tid>>7)&1 (i-half), g=tid>>8 (frame group {0,1,2}/{3,4})
    {
        const int c = tid & 127, h = (tid >> 7) & 1, g = tid >> 8;
        const int fb = g ? 3 : 0, nf = g ? 2 : 3;
        float acc[3][7];
        #pragma unroll
        for (int ff = 0; ff < 3; ++ff)
            #pragma unroll
            for (int p = 0; p < 7; ++p) acc[ff][p] = 0.f;

        const float4* wq = (const float4*)(wsf + WS_W2P4);
        for (int it = 0; it < 8; ++it) {
            const int itg = h * 8 + it;
            float4 wv[5];
            #pragma unroll
            for (int k = 0; k < 5; ++k) wv[k] = wq[(k * 16 + itg) * 128 + c];
            #pragma unroll
            for (int q = 0; q < 11; ++q) {
                float4 xv[3];
                #pragma unroll
                for (int ff = 0; ff < 3; ++ff)
                    if (ff < nf) xv[ff] = *(const float4*)&y1L[(fb + ff) * 704 + q * 64 + itg * 4];
                #pragma unroll
                for (int k = 0; k < 5; ++k) {
                    const int p = q - k;
                    if (p < 0 || p > 6) continue;
                    #pragma unroll
                    for (int ff = 0; ff < 3; ++ff)
                        if (ff < nf) acc[ff][p] += dot4(wv[k], xv[ff]);
                }
            }
        }
        if (h == 1) {
            #pragma unroll
            for (int ff = 0; ff < 3; ++ff)
                if (ff < nf)
                    #pragma unroll
                    for (int p = 0; p < 7; ++p)
                        redL[((fb + ff) * 7 + p) * 128 + c] = acc[ff][p];
        }
        __syncthreads();
        if (h == 0) {
            const float bias = b2[c];
            #pragma unroll
            for (int ff = 0; ff < 3; ++ff)
                if (ff < nf) {
                    const int f = fb + ff;
                    #pragma unroll
                    for (int p = 0; p < 7; ++p) {
                        const float v = elu1(acc[ff][p] + redL[(f * 7 + p) * 128 + c] + bias);
                        y2L[f * 896 + p * 128 + c] = v;
                        if (blk == 239 && f == 4 && p >= 3)
                            out[OFF_S3 + 3 * 512 + c * 4 + (p - 3)] = v;
                    }
                }
        }
        __syncthreads();
    }

    // ================= P2: conv3 (128->256, k=5), 3 positions, 5 frames =================
    {
        const int c = tid & 255, h = tid >> 8;
        float acc[5][3];
        #pragma unroll
        for (int ff = 0; ff < 5; ++ff) { acc[ff][0] = acc[ff][1] = acc[ff][2] = 0.f; }

        const float4* wq = (const float4*)(wsf + WS_W3P4);
        for (int it = 0; it < 16; ++it) {
            const int itg = h * 16 + it;
            float4 wv[5];
            #pragma unroll
            for (int k = 0; k < 5; ++k) wv[k] = wq[(k * 32 + itg) * 256 + c];
            #pragma unroll
            for (int q = 0; q < 7; ++q) {
                float4 xv[5];
                #pragma unroll
                for (int ff = 0; ff < 5; ++ff)
                    xv[ff] = *(const float4*)&y2L[ff * 896 + q * 128 + itg * 4];
                #pragma unroll
                for (int k = 0; k < 5; ++k) {
                    const int p = q - k;
                    if (p < 0 || p > 2) continue;
                    #pragma unroll
                    for (int ff = 0; ff < 5; ++ff) acc[ff][p] += dot4(wv[k], xv[ff]);
                }
            }
        }
        if (h == 1) {
            #pragma unroll
            for (int ff = 0; ff < 5; ++ff)
                #pragma unroll
                for (int p = 0; p < 3; ++p) redL[(ff * 3 + p) * 256 + c] = acc[ff][p];
        }
        __syncthreads();
        if (h == 0) {
            const float bias = b3[c];
            #pragma unroll
            for (int ff = 0; ff < 5; ++ff)
                #pragma unroll
                for (int p = 0; p < 3; ++p) {
                    const float v = elu1(acc[ff][p] + redL[(ff * 3 + p) * 256 + c] + bias);
                    y3L[ff * 768 + p * 256 + c] = v;
                    if (blk == 239 && ff == 4 && p >= 1)
                        out[OFF_S4 + 3 * 512 + c * 2 + (p - 1)] = v;
                }
        }
        __syncthreads();
    }

    // ================= P3: conv4 (256->512, k=3): 256 thr x 2 ch =================
    if (tid < 256) {
        const int c0 = tid, c1 = tid + 256;
        float a0[5], a1[5];
        #pragma unroll
        for (int ff = 0; ff < 5; ++ff) { a0[ff] = 0.f; a1[ff] = 0.f; }
        const float4* wq = (const float4*)(wsf + WS_W4P4);
        for (int rc = 0; rc < 192; ++rc) {
            const float4 w0 = wq[rc * 512 + c0];
            const float4 w1v = wq[rc * 512 + c1];
            #pragma unroll
            for (int ff = 0; ff < 5; ++ff) {
                const float4 xv = *(const float4*)&y3L[ff * 768 + rc * 4];
                a0[ff] += dot4(w0, xv);
                a1[ff] += dot4(w1v, xv);
            }
        }
        const float bi0 = b4[c0], bi1 = b4[c1];
        #pragma unroll
        for (int ff = 0; ff < 5; ++ff) {
            zsL[ff * 512 + c0] = elu1(a0[ff] + bi0);
            zsL[ff * 512 + c1] = elu1(a1[ff] + bi1);
        }
    }
    if (tid < 10) mk[tid / 5][tid % 5] = ~0ull;
    __syncthreads();

    // ================= P4: RVQ, 8 stages =================
    if (tid < 320) {
        const float v = zsL[wid * 512 + lane];
        rs[tid] = v;
        float ss = v * v;
        #pragma unroll
        for (int m = 1; m < 64; m <<= 1) ss += __shfl_xor(ss, m);
        if (lane == 0) rnS[wid] = ss;
    }
    __syncthreads();

    const int c0 = tid << 1;
    for (int s = 0; s < NCB; ++s) {
        const float4* cbq = (const float4*)(wsf + WS_CBP4) + (size_t)s * 16384;
        float dA[5], dB[5];
        #pragma unroll
        for (int ff = 0; ff < 5; ++ff) { dA[ff] = 0.f; dB[ff] = 0.f; }

        for (int dc = 0; dc < 16; ++dc) {
            const float4 la = cbq[dc * 1024 + c0];
            const float4 lb = cbq[dc * 1024 + c0 + 1];
            #pragma unroll
            for (int ff = 0; ff < 5; ++ff) {
                const float4 rv = *(const float4*)&rs[ff * 64 + dc * 4];
                dA[ff] += dot4(la, rv);
                dB[ff] += dot4(lb, rv);
            }
        }
        const float2 nn = *(const float2*)(wsf + WS_NRM + s * CBS + c0);
        unsigned long long key[5];
        #pragma unroll
        for (int ff = 0; ff < 5; ++ff) {
            const float rn = rnS[ff];
            const float da = (rn + nn.x) - 2.f * dA[ff];
            const float db = (rn + nn.y) - 2.f * dB[ff];
            const unsigned long long ka = ((unsigned long long)fkey(da) << 32) | (unsigned)c0;
            const unsigned long long kb = ((unsigned long long)fkey(db) << 32) | (unsigned)(c0 + 1);
            key[ff] = ka < kb ? ka : kb;
        }
        #pragma unroll
        for (int m = 1; m < 64; m <<= 1) {
            #pragma unroll
            for (int ff = 0; ff < 5; ++ff) {
                const unsigned long long o = __shfl_xor(key[ff], m);
                if (o < key[ff]) key[ff] = o;
            }
        }
        if (lane == 0) {
            #pragma unroll
            for (int ff = 0; ff < 5; ++ff) atomicMin(&mk[s & 1][ff], key[ff]);
        }
        __syncthreads();

        if (tid < 5)
            out[b * (NCB * NF) + s * NF + (f0 + tid)]
                = (float)(unsigned)(mk[s & 1][tid] & 0xFFFFFFFFull);
        if (tid < 320) {
            const int idx = (int)(unsigned)(mk[s & 1][wid] & 0xFFFFFFFFull);
            const float qv = cbs[(size_t)(s * CBS + idx) * CBD + lane];
            zqL[wid * 512 + s * 64 + lane] = qv;
            if (s < NCB - 1) {
                const float nr = zsL[wid * 512 + (s + 1) * 64 + lane] + (rs[tid] - qv);
                rs[tid] = nr;
                float ss = nr * nr;
                #pragma unroll
                for (int m = 1; m < 64; m <<= 1) ss += __shfl_xor(ss, m);
                if (lane == 0) rnS[wid] = ss;
            }
        }
        if (tid >= 320 && tid < 325) mk[(s + 1) & 1][tid - 320] = ~0ull;
        __syncthreads();
    }

    // ================= P5: head GEMV (256 outputs x 5 frames, K=512) =================
    {
        const int oc = tid & 255, h = tid >> 8;
        const float4* hq = (const float4*)(wsf + WS_HW4);
        float acc[5];
        #pragma unroll
        for (int ff = 0; ff < 5; ++ff) acc[ff] = 0.f;
        for (int rc = 0; rc < 64; ++rc) {
            const float4 wv = hq[(h * 64 + rc) * 256 + oc];
            #pragma unroll
            for (int ff = 0; ff < 5; ++ff) {
                const float4 xv = *(const float4*)&zqL[ff * 512 + h * 256 + rc * 4];
                acc[ff] += dot4(wv, xv);
            }
        }
        if (h == 1) {
            #pragma unroll
            for (int ff = 0; ff < 5; ++ff) redL[oc * 5 + ff] = acc[ff];
        }
        __syncthreads();
        if (h == 0) {
            const float bias = hb[oc];
            const int hh = oc >> 6, o = oc & 63;
            #pragma unroll
            for (int ff = 0; ff < 5; ++ff)
                out[OFF_LOG + ((size_t)(b * 4 + hh) * NF + (f0 + ff)) * 64 + o]
                    = acc[ff] + redL[oc * 5 + ff] + bias;
        }
    }
}

// ================= fallback (round-2 fused kernel, used if ws too small) =================
__global__ __launch_bounds__(256)
void enc_fused_kernel(const float* __restrict__ audio,
                      const float* __restrict__ w1, const float* __restrict__ b1,
                      const float* __restrict__ w2, const float* __restrict__ b2,
                      const float* __restrict__ w3, const float* __restrict__ b3,
                      const float* __restrict__ w4, const float* __restrict__ b4,
                      const float* __restrict__ cbs,
                      const float* __restrict__ hw, const float* __restrict__ hb,
                      float* __restrict__ out)
{
    const int tid = threadIdx.x;
    const int g = tid >> 4, sub = tid & 15, j0 = sub << 2;
    const int bf = blockIdx.x, b = bf / NF, f = bf - b * NF;
    const int t = f * HOP + (HOP - 1);

    __shared__ __align__(16) float ash[17];
    __shared__ __align__(16) float y1s[11 * 64];
    __shared__ __align__(16) float y2s[7 * 128];
    __shared__ __align__(16) float y3s[3 * 256];
    __shared__ __align__(16) float in_l[2240];
    __shared__ __align__(16) float zs[512];
    __shared__ __align__(16) float zqs[512];
    __shared__ __align__(16) float rsl[64];
    __shared__ float rdd[16]; __shared__ int rdi[16]; __shared__ int bidx_s;

    if (tid < 17) ash[tid] = audio[b * T_IN + (t - 16) + tid];
    __syncthreads();
    for (int j = tid; j < 11 * 64; j += 256) {
        const int p = j >> 6, o = j & 63;
        float acc = b1[o];
        for (int k = 0; k < 7; ++k) acc += w1[o * 7 + k] * ash[p + k];
        y1s[p * 64 + o] = elu1(acc);
    }
    __syncthreads();
    for (int j = tid; j < 7 * 320; j += 256) {
        const int p = j / 320, r = j - p * 320, i = r / 5, k = r - i * 5;
        in_l[j] = y1s[(p + k) * 64 + i];
    }
    __syncthreads();
    {
        float a[7];
        for (int ch = 0; ch < 8; ++ch) {
            const int c = g + (ch << 4);
            const float* wr = w2 + c * 320;
            for (int p = 0; p < 7; ++p) a[p] = 0.f;
            for (int st = 0; st < 5; ++st) {
                const float4 wv = *(const float4*)(wr + st * 64 + j0);
                for (int p = 0; p < 7; ++p)
                    a[p] += dot4(wv, *(const float4*)&in_l[p * 320 + st * 64 + j0]);
            }
            for (int p = 0; p < 7; ++p) a[p] = red16(a[p]);
            if (sub == 0) for (int p = 0; p < 7; ++p) y2s[p * 128 + c] = elu1(a[p] + b2[c]);
        }
    }
    __syncthreads();
    for (int j = tid; j < 3 * 640; j += 256) {
        const int p = j / 640, r = j - p * 640, i = r / 5, k = r - i * 5;
        in_l[j] = y2s[(p + k) * 128 + i];
    }
    __syncthreads();
    {
        float a[3];
        for (int ch = 0; ch < 16; ++ch) {
            const int c = g + (ch << 4);
            const float* wr = w3 + c * 640;
            a[0] = a[1] = a[2] = 0.f;
            for (int st = 0; st < 10; ++st) {
                const float4 wv = *(const float4*)(wr + st * 64 + j0);
                for (int p = 0; p < 3; ++p)
                    a[p] += dot4(wv, *(const float4*)&in_l[p * 640 + st * 64 + j0]);
            }
            for (int p = 0; p < 3; ++p) a[p] = red16(a[p]);
            if (sub == 0) for (int p = 0; p < 3; ++p) y3s[p * 256 + c] = elu1(a[p] + b3[c]);
        }
    }
    __syncthreads();
    for (int j = tid; j < 768; j += 256) { const int i = j / 3, k = j - i * 3; in_l[j] = y3s[k * 256 + i]; }
    __syncthreads();
    for (int ch = 0; ch < 32; ++ch) {
        const int c = g + (ch << 4);
        const float* wr = w4 + c * 768;
        float a = 0.f;
        for (int st = 0; st < 12; ++st)
            a += dot4(*(const float4*)(wr + st * 64 + j0), *(const float4*)&in_l[st * 64 + j0]);
        a = red16(a);
        if (sub == 0) zs[c] = elu1(a + b4[c]);
    }
    __syncthreads();
    if (tid < 64) rsl[tid] = zs[tid];
    __syncthreads();
    for (int s = 0; s < NCB; ++s) {
        const float* cb = cbs + s * (CBS * CBD);
        const float4 rv = *(const float4*)(rsl + j0);
        const float rn = red16(dot4(rv, rv));
        float bestd = 3.402823466e38f; int besti = 0;
        const int cc0 = g * 64;
        for (int cc = 0; cc < 64; ++cc) {
            const int c = cc0 + cc;
            const float4 cv = *(const float4*)(cb + c * CBD + j0);
            const float dt = red16(dot4(cv, rv));
            const float nnv = red16(dot4(cv, cv));
            const float d = rn + nnv - 2.f * dt;
            if (d < bestd) { bestd = d; besti = c; }
        }
        if (sub == 0) { rdd[g] = bestd; rdi[g] = besti; }
        __syncthreads();
        if (tid == 0) {
            float bd = rdd[0]; int bi = rdi[0];
            for (int q = 1; q < 16; ++q) if (rdd[q] < bd) { bd = rdd[q]; bi = rdi[q]; }
            bidx_s = bi;
            out[b * (NCB * NF) + s * NF + f] = (float)bi;
        }
        __syncthreads();
        const int idx = bidx_s;
        if (g == 0) {
            const float4 q4 = *(const float4*)(cb + idx * CBD + j0);
            *(float4*)&zqs[s * 64 + j0] = q4;
            if (s < NCB - 1) {
                const float4 zn = *(const float4*)&zs[(s + 1) * 64 + j0];
                float4 nr;
                nr.x = zn.x + (rv.x - q4.x); nr.y = zn.y + (rv.y - q4.y);
                nr.z = zn.z + (rv.z - q4.z); nr.w = zn.w + (rv.w - q4.w);
                *(float4*)&rsl[j0] = nr;
            }
        }
        __syncthreads();
    }
    for (int oo = 0; oo < 16; ++oo) {
        const int oc = g + (oo << 4);
        const float* wr = hw + oc * 512;
        float a = 0.f;
        for (int st = 0; st < 8; ++st)
            a += dot4(*(const float4*)(wr + st * 64 + j0), *(const float4*)&zqs[st * 64 + j0]);
        a = red16(a);
        if (sub == 0) {
            const int h = oc >> 6, o = oc & 63;
            out[OFF_LOG + ((b * 4 + h) * NF + f) * 64 + o] = a + hb[oc];
        }
    }
    if (f == NF - 1) {
        if (tid < 6) out[OFF_S1 + b * 6 + tid] = audio[b * T_IN + (T_IN - 6) + tid];
        out[OFF_S2 + b * 256 + tid] = y1s[(7 + (tid & 3)) * 64 + (tid >> 2)];
        for (int j = tid; j < 512; j += 256)
            out[OFF_S3 + b * 512 + j] = y2s[(3 + (j & 3)) * 128 + (j >> 2)];
        for (int j = tid; j < 512; j += 256)
            out[OFF_S4 + b * 512 + j] = y3s[(1 + (j & 1)) * 256 + (j >> 1)];
    }
}

extern "C" void kernel_launch(void* const* d_in, const int* in_sizes, int n_in,
                              void* d_out, int out_size, void* d_ws, size_t ws_size,
                              hipStream_t stream) {
    const float* audio = (const float*)d_in[0];
    const float* w1 = (const float*)d_in[1];
    const float* b1 = (const float*)d_in[2];
    const float* w2 = (const float*)d_in[3];
    const float* b2 = (const float*)d_in[4];
    const float* w3 = (const float*)d_in[5];
    const float* b3 = (const float*)d_in[6];
    const float* w4 = (const float*)d_in[7];
    const float* b4 = (const float*)d_in[8];
    const float* cbs = (const float*)d_in[9];
    const float* hw = (const float*)d_in[10];
    const float* hb = (const float*)d_in[11];
    float* out = (float*)d_out;
    float* wsf = (float*)d_ws;

    if (ws_size >= WS_TOTAL * sizeof(float)) {
        prep_kernel<<<dim3(306), 256, 0, stream>>>(w2, w3, w4, hw, cbs, wsf);
        mega_kernel<<<dim3(240), 512, 0, stream>>>(audio, w1, b1, b2, b3, b4,
                                                   cbs, hb, wsf, out);
    } else {
        enc_fused_kernel<<<dim3(NB * NF), 256, 0, stream>>>(
            audio, w1, b1, w2, b2, w3, b3, w4, b4, cbs, hw, hb, out);
    }
}

// Round 7
// 245.285 us; speedup vs baseline: 3.5183x; 1.0319x over previous
//
#include <hip/hip_runtime.h>
#include <math.h>

#define HOP   240
#define T_IN  72000
#define NB    4
#define NF    300
#define NCB   8
#define CBS   1024
#define CBD   64

#define OFF_LOG 9600
#define OFF_S1  316800
#define OFF_S2  316824
#define OFF_S3  317848
#define OFF_S4  319896

// workspace layout (float offsets) — packed-float4 forms
#define WS_NRM   0          // 8192
#define WS_W2P4  8192       // 40960   [(k*16+i4)][128c][4]
#define WS_W3P4  49152      // 163840  [(k*32+i4)][256c][4]
#define WS_W4P4  212992     // 393216  [(k*64+i4)][512c][4]
#define WS_HW4   606208     // 131072  [d4][256oc][4]
#define WS_CBP4  737280     // 524288  [s][d4][1024code][4]
#define WS_TOTAL 1261568ull // floats

__device__ __forceinline__ float elu1(float x) { return x > 0.f ? x : expm1f(x); }
__device__ __forceinline__ float dot4(float4 a, float4 b) {
    return a.x * b.x + a.y * b.y + a.z * b.z + a.w * b.w;
}
__device__ __forceinline__ float red16(float v) {
    v += __shfl_xor(v, 1); v += __shfl_xor(v, 2);
    v += __shfl_xor(v, 4); v += __shfl_xor(v, 8);
    return v;
}
__device__ __forceinline__ unsigned int fkey(float f) {
    unsigned int u = __float_as_uint(f);
    return (u & 0x80000000u) ? ~u : (u | 0x80000000u);
}

// ---------- prep: coalesced packed transposes + codebook norms ----------
// dst float4[(k*(I/4) + i4)*C + c] = { src[c][(4*i4+m)*K + k] : m=0..3 }
__global__ __launch_bounds__(256)
void prep_kernel(const float* __restrict__ w2, const float* __restrict__ w3,
                 const float* __restrict__ w4, const float* __restrict__ hw,
                 const float* __restrict__ cbs, float* __restrict__ wsf)
{
    const int bid = blockIdx.x;
    const float* src; float* dst;
    int C, I, K, c0, i0;
    bool do_norm = false; float* nrmp = nullptr;
    if (bid < 2)       { src = w2; dst = wsf + WS_W2P4; C = 128;  I = 64;  K = 5; c0 = bid * 64;        i0 = 0; }
    else if (bid < 10) { const int e = bid - 2;  src = w3; dst = wsf + WS_W3P4; C = 256;  I = 128; K = 5; c0 = (e >> 1) * 64; i0 = (e & 1) * 64; }
    else if (bid < 42) { const int e = bid - 10; src = w4; dst = wsf + WS_W4P4; C = 512;  I = 256; K = 3; c0 = (e >> 2) * 64; i0 = (e & 3) * 64; }
    else if (bid < 74) { const int e = bid - 42; src = hw; dst = wsf + WS_HW4;  C = 256;  I = 512; K = 1; c0 = (e & 3) * 64;  i0 = (e >> 2) * 64; }
    else {
        const int e = bid - 74, book = e >> 4;
        src = cbs + (size_t)book * 65536; dst = wsf + WS_CBP4 + (size_t)book * 65536;
        C = 1024; I = 64; K = 1; c0 = (e & 15) * 64; i0 = 0;
        do_norm = true; nrmp = wsf + WS_NRM + book * 1024;
    }
    const int L = I * K;
    const int lane = threadIdx.x & 63, q = threadIdx.x >> 6;

    __shared__ float tS[64][65];
    __shared__ float npart[4][64];

    for (int k = 0; k < K; ++k) {
        // load tile: tS[c_local][ii] = src[c0+cl][ (i0+ii)*K + k ]   (lane = ii)
        #pragma unroll
        for (int r = 0; r < 16; ++r) {
            const int cl = q * 16 + r;
            tS[cl][lane] = src[(size_t)(c0 + cl) * L + (i0 + lane) * K + k];
        }
        __syncthreads();
        if (do_norm && k == 0) {
            float s = 0.f;
            #pragma unroll
            for (int j = 0; j < 16; ++j) { const float v = tS[lane][q * 16 + j]; s += v * v; }
            npart[q][lane] = s;
        }
        // store packed: lane = c, coalesced float4
        #pragma unroll
        for (int jj = 0; jj < 4; ++jj) {
            const int j = q * 4 + jj;                    // i-quad within chunk
            float4 v;
            v.x = tS[lane][4 * j + 0];
            v.y = tS[lane][4 * j + 1];
            v.z = tS[lane][4 * j + 2];
            v.w = tS[lane][4 * j + 3];
            ((float4*)dst)[(size_t)(k * (I >> 2) + (i0 >> 2) + j) * C + (c0 + lane)] = v;
        }
        __syncthreads();
    }
    if (do_norm && threadIdx.x < 64)
        nrmp[c0 + threadIdx.x] = npart[0][threadIdx.x] + npart[1][threadIdx.x]
                               + npart[2][threadIdx.x] + npart[3][threadIdx.x];
}

// ---------- mega kernel: conv1..conv4 + RVQ + head, 3 frames/block, G=400 ----------
__global__ __launch_bounds__(512, 4)
void mega_kernel(const float* __restrict__ audio,
                 const float* __restrict__ w1, const float* __restrict__ b1,
                 const float* __restrict__ b2, const float* __restrict__ b3,
                 const float* __restrict__ b4, const float* __restrict__ cbs,
                 const float* __restrict__ hb, const float* __restrict__ wsf,
                 float* __restrict__ out)
{
    const int blk = blockIdx.x;            // 0..399
    const int b   = blk / 100;
    const int fi  = blk - b * 100;
    const int f0  = fi * 3;
    const bool tail = (fi == 99);
    const int tid = threadIdx.x;
    const int lane = tid & 63, wid = tid >> 6;

    __shared__ float ashL[3][18];
    __shared__ __align__(16) float y1L[3 * 704];   // [f][q*64+o], q<11
    __shared__ __align__(16) float y2L[3 * 896];   // [f][p*128+c], p<7
    __shared__ __align__(16) float y3L[3 * 768];   // [f][p*256+c], p<3
    __shared__ __align__(16) float zsL[3 * 512];
    __shared__ __align__(16) float zqL[3 * 512];
    __shared__ __align__(16) float rs[192];
    __shared__ float redL[2688];                   // conv2 [3*7][128] / conv3 [3*3][256] / head [256*3]
    __shared__ float rnS[3];
    __shared__ unsigned long long mk[2][3];

    // ================= P0: conv1 (1->64, k=7) at 11 positions, 3 frames =================
    if (tid < 51) {
        const int f = tid / 17, j = tid - f * 17;
        ashL[f][j] = audio[b * T_IN + (f0 + f) * HOP + 223 + j];
    }
    if (tail && tid < 6) out[OFF_S1 + b * 6 + tid] = audio[b * T_IN + (T_IN - 6) + tid];
    if (tid < 6) mk[tid / 3][tid % 3] = ~0ull;
    __syncthreads();

    if (tid < 192) {
        const int f = tid >> 6, o = tid & 63;
        float wv[7];
        #pragma unroll
        for (int k = 0; k < 7; ++k) wv[k] = w1[o * 7 + k];
        const float bias = b1[o];
        float y1r[11];
        #pragma unroll
        for (int p = 0; p < 11; ++p) {
            float a = bias;
            #pragma unroll
            for (int k = 0; k < 7; ++k) a += wv[k] * ashL[f][p + k];
            y1r[p] = elu1(a);
            y1L[f * 704 + p * 64 + o] = y1r[p];
        }
        if (tail && f == 2) {
            #pragma unroll
            for (int j = 0; j < 4; ++j) out[OFF_S2 + b * 256 + o * 4 + j] = y1r[7 + j];
        }
    }
    __syncthreads();

    // ================= P1: conv2 (64->128, k=5), 7 positions =================
    // threads: c=tid&127, h=(tid>>7)&1 (i-half), g=tid>>8 (frames {0,1} / {2})
    {
        const int c = tid & 127, h = (tid >> 7) & 1, g = tid >> 8;
        const int fb = g * 2, nf = g ? 1 : 2;
        float acc[2][7];
        #pragma unroll
        for (int ff = 0; ff < 2; ++ff)
            #pragma unroll
            for (int p = 0; p < 7; ++p) acc[ff][p] = 0.f;

        const float4* wq = (const float4*)(wsf + WS_W2P4);
        for (int it = 0; it < 8; ++it) {
            const int itg = h * 8 + it;
            float4 wv[5];
            #pragma unroll
            for (int k = 0; k < 5; ++k) wv[k] = wq[(k * 16 + itg) * 128 + c];
            #pragma unroll
            for (int q = 0; q < 11; ++q) {
                float4 xv[2];
                #pragma unroll
                for (int ff = 0; ff < 2; ++ff)
                    if (ff < nf) xv[ff] = *(const float4*)&y1L[(fb + ff) * 704 + q * 64 + itg * 4];
                #pragma unroll
                for (int k = 0; k < 5; ++k) {
                    const int p = q - k;
                    if (p < 0 || p > 6) continue;
                    #pragma unroll
                    for (int ff = 0; ff < 2; ++ff)
                        if (ff < nf) acc[ff][p] += dot4(wv[k], xv[ff]);
                }
            }
        }
        if (h == 1) {
            #pragma unroll
            for (int ff = 0; ff < 2; ++ff)
                if (ff < nf)
                    #pragma unroll
                    for (int p = 0; p < 7; ++p)
                        redL[((fb + ff) * 7 + p) * 128 + c] = acc[ff][p];
        }
        __syncthreads();
        if (h == 0) {
            const float bias = b2[c];
            #pragma unroll
            for (int ff = 0; ff < 2; ++ff)
                if (ff < nf) {
                    const int f = fb + ff;
                    #pragma unroll
                    for (int p = 0; p < 7; ++p) {
                        const float v = elu1(acc[ff][p] + redL[(f * 7 + p) * 128 + c] + bias);
                        y2L[f * 896 + p * 128 + c] = v;
                        if (tail && f == 2 && p >= 3)
                            out[OFF_S3 + b * 512 + c * 4 + (p - 3)] = v;
                    }
                }
        }
        __syncthreads();
    }

    // ================= P2: conv3 (128->256, k=5), 3 positions, 3 frames =================
    {
        const int c = tid & 255, h = tid >> 8;
        float acc[3][3];
        #pragma unroll
        for (int ff = 0; ff < 3; ++ff) { acc[ff][0] = acc[ff][1] = acc[ff][2] = 0.f; }

        const float4* wq = (const float4*)(wsf + WS_W3P4);
        for (int it = 0; it < 16; ++it) {
            const int itg = h * 16 + it;
            float4 wv[5];
            #pragma unroll
            for (int k = 0; k < 5; ++k) wv[k] = wq[(k * 32 + itg) * 256 + c];
            #pragma unroll
            for (int q = 0; q < 7; ++q) {
                float4 xv[3];
                #pragma unroll
                for (int ff = 0; ff < 3; ++ff)
                    xv[ff] = *(const float4*)&y2L[ff * 896 + q * 128 + itg * 4];
                #pragma unroll
                for (int k = 0; k < 5; ++k) {
                    const int p = q - k;
                    if (p < 0 || p > 2) continue;
                    #pragma unroll
                    for (int ff = 0; ff < 3; ++ff) acc[ff][p] += dot4(wv[k], xv[ff]);
                }
            }
        }
        if (h == 1) {
            #pragma unroll
            for (int ff = 0; ff < 3; ++ff)
                #pragma unroll
                for (int p = 0; p < 3; ++p) redL[(ff * 3 + p) * 256 + c] = acc[ff][p];
        }
        __syncthreads();
        if (h == 0) {
            const float bias = b3[c];
            #pragma unroll
            for (int ff = 0; ff < 3; ++ff)
                #pragma unroll
                for (int p = 0; p < 3; ++p) {
                    const float v = elu1(acc[ff][p] + redL[(ff * 3 + p) * 256 + c] + bias);
                    y3L[ff * 768 + p * 256 + c] = v;
                    if (tail && ff == 2 && p >= 1)
                        out[OFF_S4 + b * 512 + c * 2 + (p - 1)] = v;
                }
        }
        __syncthreads();
    }

    // ================= P3: conv4 (256->512, k=3): 512 thr x 1 ch =================
    {
        const int c = tid;
        float acc[3] = {0.f, 0.f, 0.f};
        const float4* wq = (const float4*)(wsf + WS_W4P4);
        for (int rc = 0; rc < 192; ++rc) {
            const float4 w0 = wq[rc * 512 + c];
            #pragma unroll
            for (int ff = 0; ff < 3; ++ff) {
                const float4 xv = *(const float4*)&y3L[ff * 768 + rc * 4];
                acc[ff] += dot4(w0, xv);
            }
        }
        const float bias = b4[c];
        #pragma unroll
        for (int ff = 0; ff < 3; ++ff)
            zsL[ff * 512 + c] = elu1(acc[ff] + bias);
    }
    __syncthreads();

    // ================= P4: RVQ, 8 stages =================
    if (tid < 192) {
        const float v = zsL[wid * 512 + lane];
        rs[tid] = v;
        float ss = v * v;
        #pragma unroll
        for (int m = 1; m < 64; m <<= 1) ss += __shfl_xor(ss, m);
        if (lane == 0) rnS[wid] = ss;
    }
    __syncthreads();

    const int c0 = tid << 1;
    for (int s = 0; s < NCB; ++s) {
        const float4* cbq = (const float4*)(wsf + WS_CBP4) + (size_t)s * 16384;
        float dA[3], dB[3];
        #pragma unroll
        for (int ff = 0; ff < 3; ++ff) { dA[ff] = 0.f; dB[ff] = 0.f; }

        for (int dc = 0; dc < 16; ++dc) {
            const float4 la = cbq[dc * 1024 + c0];
            const float4 lb = cbq[dc * 1024 + c0 + 1];
            #pragma unroll
            for (int ff = 0; ff < 3; ++ff) {
                const float4 rv = *(const float4*)&rs[ff * 64 + dc * 4];
                dA[ff] += dot4(la, rv);
                dB[ff] += dot4(lb, rv);
            }
        }
        const float2 nn = *(const float2*)(wsf + WS_NRM + s * CBS + c0);
        unsigned long long key[3];
        #pragma unroll
        for (int ff = 0; ff < 3; ++ff) {
            const float rn = rnS[ff];
            const float da = (rn + nn.x) - 2.f * dA[ff];
            const float db = (rn + nn.y) - 2.f * dB[ff];
            const unsigned long long ka = ((unsigned long long)fkey(da) << 32) | (unsigned)c0;
            const unsigned long long kb = ((unsigned long long)fkey(db) << 32) | (unsigned)(c0 + 1);
            key[ff] = ka < kb ? ka : kb;
        }
        #pragma unroll
        for (int m = 1; m < 64; m <<= 1) {
            #pragma unroll
            for (int ff = 0; ff < 3; ++ff) {
                const unsigned long long o = __shfl_xor(key[ff], m);
                if (o < key[ff]) key[ff] = o;
            }
        }
        if (lane == 0) {
            #pragma unroll
            for (int ff = 0; ff < 3; ++ff) atomicMin(&mk[s & 1][ff], key[ff]);
        }
        __syncthreads();

        if (tid < 3)
            out[b * (NCB * NF) + s * NF + (f0 + tid)]
                = (float)(unsigned)(mk[s & 1][tid] & 0xFFFFFFFFull);
        if (tid < 192) {
            const int idx = (int)(unsigned)(mk[s & 1][wid] & 0xFFFFFFFFull);
            const float qv = cbs[(size_t)(s * CBS + idx) * CBD + lane];
            zqL[wid * 512 + s * 64 + lane] = qv;
            if (s < NCB - 1) {
                const float nr = zsL[wid * 512 + (s + 1) * 64 + lane] + (rs[tid] - qv);
                rs[tid] = nr;
                float ss = nr * nr;
                #pragma unroll
                for (int m = 1; m < 64; m <<= 1) ss += __shfl_xor(ss, m);
                if (lane == 0) rnS[wid] = ss;
            }
        }
        if (tid >= 192 && tid < 195) mk[(s + 1) & 1][tid - 192] = ~0ull;
        __syncthreads();
    }

    // ================= P5: head GEMV (256 outputs x 3 frames, K=512) =================
    {
        const int oc = tid & 255, h = tid >> 8;
        const float4* hq = (const float4*)(wsf + WS_HW4);
        float acc[3] = {0.f, 0.f, 0.f};
        for (int rc = 0; rc < 64; ++rc) {
            const float4 wv = hq[(h * 64 + rc) * 256 + oc];
            #pragma unroll
            for (int ff = 0; ff < 3; ++ff) {
                const float4 xv = *(const float4*)&zqL[ff * 512 + h * 256 + rc * 4];
                acc[ff] += dot4(wv, xv);
            }
        }
        if (h == 1) {
            #pragma unroll
            for (int ff = 0; ff < 3; ++ff) redL[oc * 3 + ff] = acc[ff];
        }
        __syncthreads();
        if (h == 0) {
            const float bias = hb[oc];
            const int hh = oc >> 6, o = oc & 63;
            #pragma unroll
            for (int ff = 0; ff < 3; ++ff)
                out[OFF_LOG + ((size_t)(b * 4 + hh) * NF + (f0 + ff)) * 64 + o]
                    = acc[ff] + redL[oc * 3 + ff] + bias;
        }
    }
}

// ================= fallback (round-2 fused kernel, used if ws too small) =================
__global__ __launch_bounds__(256)
void enc_fused_kernel(const float* __restrict__ audio,
                      const float* __restrict__ w1, const float* __restrict__ b1,
                      const float* __restrict__ w2, const float* __restrict__ b2,
                      const float* __restrict__ w3, const float* __restrict__ b3,
                      const float* __restrict__ w4, const float* __restrict__ b4,
                      const float* __restrict__ cbs,
                      const float* __restrict__ hw, const float* __restrict__ hb,
                      float* __restrict__ out)
{
    const int tid = threadIdx.x;
    const int g = tid >> 4, sub = tid & 15, j0 = sub << 2;
    const int bf = blockIdx.x, b = bf / NF, f = bf - b * NF;
    const int t = f * HOP + (HOP - 1);

    __shared__ __align__(16) float ash[17];
    __shared__ __align__(16) float y1s[11 * 64];
    __shared__ __align__(16) float y2s[7 * 128];
    __shared__ __align__(16) float y3s[3 * 256];
    __shared__ __align__(16) float in_l[2240];
    __shared__ __align__(16) float zs[512];
    __shared__ __align__(16) float zqs[512];
    __shared__ __align__(16) float rsl[64];
    __shared__ float rdd[16]; __shared__ int rdi[16]; __shared__ int bidx_s;

    if (tid < 17) ash[tid] = audio[b * T_IN + (t - 16) + tid];
    __syncthreads();
    for (int j = tid; j < 11 * 64; j += 256) {
        const int p = j >> 6, o = j & 63;
        float acc = b1[o];
        for (int k = 0; k < 7; ++k) acc += w1[o * 7 + k] * ash[p + k];
        y1s[p * 64 + o] = elu1(acc);
    }
    __syncthreads();
    for (int j = tid; j < 7 * 320; j += 256) {
        const int p = j / 320, r = j - p * 320, i = r / 5, k = r - i * 5;
        in_l[j] = y1s[(p + k) * 64 + i];
    }
    __syncthreads();
    {
        float a[7];
        for (int ch = 0; ch < 8; ++ch) {
            const int c = g + (ch << 4);
            const float* wr = w2 + c * 320;
            for (int p = 0; p < 7; ++p) a[p] = 0.f;
            for (int st = 0; st < 5; ++st) {
                const float4 wv = *(const float4*)(wr + st * 64 + j0);
                for (int p = 0; p < 7; ++p)
                    a[p] += dot4(wv, *(const float4*)&in_l[p * 320 + st * 64 + j0]);
            }
            for (int p = 0; p < 7; ++p) a[p] = red16(a[p]);
            if (sub == 0) for (int p = 0; p < 7; ++p) y2s[p * 128 + c] = elu1(a[p] + b2[c]);
        }
    }
    __syncthreads();
    for (int j = tid; j < 3 * 640; j += 256) {
        const int p = j / 640, r = j - p * 640, i = r / 5, k = r - i * 5;
        in_l[j] = y2s[(p + k) * 128 + i];
    }
    __syncthreads();
    {
        float a[3];
        for (int ch = 0; ch < 16; ++ch) {
            const int c = g + (ch << 4);
            const float* wr = w3 + c * 640;
            a[0] = a[1] = a[2] = 0.f;
            for (int st = 0; st < 10; ++st) {
                const float4 wv = *(const float4*)(wr + st * 64 + j0);
                for (int p = 0; p < 3; ++p)
                    a[p] += dot4(wv, *(const float4*)&in_l[p * 640 + st * 64 + j0]);
            }
            for (int p = 0; p < 3; ++p) a[p] = red16(a[p]);
            if (sub == 0) for (int p = 0; p < 3; ++p) y3s[p * 256 + c] = elu1(a[p] + b3[c]);
        }
    }
    __syncthreads();
    for (int j = tid; j < 768; j += 256) { const int i = j / 3, k = j - i * 3; in_l[j] = y3s[k * 256 + i]; }
    __syncthreads();
    for (int ch = 0; ch < 32; ++ch) {
        const int c = g + (ch << 4);
        const float* wr = w4 + c * 768;
        float a = 0.f;
        for (int st = 0; st < 12; ++st)
            a += dot4(*(const float4*)(wr + st * 64 + j0), *(const float4*)&in_l[st * 64 + j0]);
        a = red16(a);
        if (sub == 0) zs[c] = elu1(a + b4[c]);
    }
    __syncthreads();
    if (tid < 64) rsl[tid] = zs[tid];
    __syncthreads();
    for (int s = 0; s < NCB; ++s) {
        const float* cb = cbs + s * (CBS * CBD);
        const float4 rv = *(const float4*)(rsl + j0);
        const float rn = red16(dot4(rv, rv));
        float bestd = 3.402823466e38f; int besti = 0;
        const int cc0 = g * 64;
        for (int cc = 0; cc < 64; ++cc) {
            const int c = cc0 + cc;
            const float4 cv = *(const float4*)(cb + c * CBD + j0);
            const float dt = red16(dot4(cv, rv));
            const float nnv = red16(dot4(cv, cv));
            const float d = rn + nnv - 2.f * dt;
            if (d < bestd) { bestd = d; besti = c; }
        }
        if (sub == 0) { rdd[g] = bestd; rdi[g] = besti; }
        __syncthreads();
        if (tid == 0) {
            float bd = rdd[0]; int bi = rdi[0];
            for (int q = 1; q < 16; ++q) if (rdd[q] < bd) { bd = rdd[q]; bi = rdi[q]; }
            bidx_s = bi;
            out[b * (NCB * NF) + s * NF + f] = (float)bi;
        }
        __syncthreads();
        const int idx = bidx_s;
        if (g == 0) {
            const float4 q4 = *(const float4*)(cb + idx * CBD + j0);
            *(float4*)&zqs[s * 64 + j0] = q4;
            if (s < NCB - 1) {
                const float4 zn = *(const float4*)&zs[(s + 1) * 64 + j0];
                float4 nr;
                nr.x = zn.x + (rv.x - q4.x); nr.y = zn.y + (rv.y - q4.y);
                nr.z = zn.z + (rv.z - q4.z); nr.w = zn.w + (rv.w - q4.w);
                *(float4*)&rsl[j0] = nr;
            }
        }
        __syncthreads();
    }
    for (int oo = 0; oo < 16; ++oo) {
        const int oc = g + (oo << 4);
        const float* wr = hw + oc * 512;
        float a = 0.f;
        for (int st = 0; st < 8; ++st)
            a += dot4(*(const float4*)(wr + st * 64 + j0), *(const float4*)&zqs[st * 64 + j0]);
        a = red16(a);
        if (sub == 0) {
            const int h = oc >> 6, o = oc & 63;
            out[OFF_LOG + ((b * 4 + h) * NF + f) * 64 + o] = a + hb[oc];
        }
    }
    if (f == NF - 1) {
        if (tid < 6) out[OFF_S1 + b * 6 + tid] = audio[b * T_IN + (T_IN - 6) + tid];
        out[OFF_S2 + b * 256 + tid] = y1s[(7 + (tid & 3)) * 64 + (tid >> 2)];
        for (int j = tid; j < 512; j += 256)
            out[OFF_S3 + b * 512 + j] = y2s[(3 + (j & 3)) * 128 + (j >> 2)];
        for (int j = tid; j < 512; j += 256)
            out[OFF_S4 + b * 512 + j] = y3s[(1 + (j & 1)) * 256 + (j >> 1)];
    }
}

extern "C" void kernel_launch(void* const* d_in, const int* in_sizes, int n_in,
                              void* d_out, int out_size, void* d_ws, size_t ws_size,
                              hipStream_t stream) {
    const float* audio = (const float*)d_in[0];
    const float* w1 = (const float*)d_in[1];
    const float* b1 = (const float*)d_in[2];
    const float* w2 = (const float*)d_in[3];
    const float* b2 = (const float*)d_in[4];
    const float* w3 = (const float*)d_in[5];
    const float* b3 = (const float*)d_in[6];
    const float* w4 = (const float*)d_in[7];
    const float* b4 = (const float*)d_in[8];
    const float* cbs = (const float*)d_in[9];
    const float* hw = (const float*)d_in[10];
    const float* hb = (const float*)d_in[11];
    float* out = (float*)d_out;
    float* wsf = (float*)d_ws;

    if (ws_size >= WS_TOTAL * sizeof(float)) {
        prep_kernel<<<dim3(202), 256, 0, stream>>>(w2, w3, w4, hw, cbs, wsf);
        mega_kernel<<<dim3(400), 512, 0, stream>>>(audio, w1, b1, b2, b3, b4,
                                                   cbs, hb, wsf, out);
    } else {
        enc_fused_kernel<<<dim3(NB * NF), 256, 0, stream>>>(
            audio, w1, b1, w2, b2, w3, b3, w4, b4, cbs, hw, hb, out);
    }
}